// Round 6
// baseline (353.636 us; speedup 1.0000x reference)
//
#include <hip/hip_runtime.h>
#include <math.h>

#define N_NODES 50000
#define N_EDGES 800000
#define FDIM 128
#define NH 8
#define NC 32
#define D1 256      // NH*NC
#define NCLS 16
#define NGRP 64
#define NEG 0.2f
#define E_TOT (N_EDGES + N_NODES)
#define NB_N 196    // (N_NODES+255)/256

typedef __attribute__((ext_vector_type(8))) unsigned short u16x8;
typedef __attribute__((ext_vector_type(8))) short short8;
typedef __attribute__((ext_vector_type(4))) float f32x4;

static __device__ __forceinline__ float bf2f(unsigned short u) {
    return __uint_as_float(((unsigned int)u) << 16);
}
static __device__ __forceinline__ unsigned short f2bf(float f) {
    unsigned int b = __float_as_uint(f);
    return (unsigned short)((b + 0x7FFFu + ((b >> 16) & 1u)) >> 16);
}

// ------ init: cnt=1, pool accums=0, W1 -> per-lane-packed bf16 B fragments ----
__global__ void k_init(const float* __restrict__ W1, unsigned short* __restrict__ w1p,
                       int* __restrict__ cnt, float* __restrict__ poolS,
                       float* __restrict__ poolC) {
    int i = blockIdx.x * 256 + threadIdx.x;
    if (i < N_NODES) cnt[i] = 1;               // self loop
    if (i < NGRP * NCLS) poolS[i] = 0.f;
    if (i < NGRP) poolC[i] = 0.f;
    if (i < FDIM * D1) {
        int ks = i >> 13;
        int r = i & 8191;
        int nt2 = r >> 9;
        int r2 = r & 511;
        int lane = r2 >> 3, e = r2 & 7;
        int k = ks * 32 + (lane >> 4) * 8 + e;
        int col = nt2 * 16 + (lane & 15);
        w1p[i] = f2bf(W1[k * D1 + col]);
    }
}

// ------ GEMM1 via MFMA bf16 (no LDS): xp1b = bf16(x)@bf16(W1), fused al1 ------
__global__ __launch_bounds__(256) void k_gemm1m(
    const float* __restrict__ x, const unsigned short* __restrict__ w1p,
    const float* __restrict__ a1s, const float* __restrict__ a1d,
    unsigned short* __restrict__ xp1b, float* __restrict__ al1s,
    float* __restrict__ al1d) {
    const int l = threadIdx.x & 63;
    const int wid = threadIdx.x >> 6;
    const int wr = wid >> 1, wc = wid & 1;
    const int l15 = l & 15, l4 = l >> 4;
    const int base = blockIdx.x * 64;
    const int r0 = base + wr * 32;

    f32x4 acc[2][8] = {};
#pragma unroll
    for (int ks = 0; ks < 4; ++ks) {
        const int kk = ks * 32 + l4 * 8;
        short8 af[2];
#pragma unroll
        for (int rt = 0; rt < 2; ++rt) {
            int row = r0 + rt * 16 + l15;
            float4 v0 = make_float4(0.f, 0.f, 0.f, 0.f), v1 = v0;
            if (row < N_NODES) {
                const float* xr = x + (size_t)row * FDIM + kk;
                v0 = *(const float4*)xr;
                v1 = *(const float4*)(xr + 4);
            }
            short8 a;
            a[0] = (short)f2bf(v0.x); a[1] = (short)f2bf(v0.y);
            a[2] = (short)f2bf(v0.z); a[3] = (short)f2bf(v0.w);
            a[4] = (short)f2bf(v1.x); a[5] = (short)f2bf(v1.y);
            a[6] = (short)f2bf(v1.z); a[7] = (short)f2bf(v1.w);
            af[rt] = a;
        }
#pragma unroll
        for (int nt = 0; nt < 8; ++nt) {
            int nt2 = wc * 8 + nt;
            short8 bf_ = *(const short8*)&w1p[(size_t)((ks * 16 + nt2) * 64 + l) * 8];
            acc[0][nt] = __builtin_amdgcn_mfma_f32_16x16x32_bf16(af[0], bf_, acc[0][nt], 0, 0, 0);
            acc[1][nt] = __builtin_amdgcn_mfma_f32_16x16x32_bf16(af[1], bf_, acc[1][nt], 0, 0, 0);
        }
    }
    // epilogue 1: bf16 stores (C/D: col=lane&15, row=(lane>>4)*4+reg)
#pragma unroll
    for (int rt = 0; rt < 2; ++rt) {
        int rbase = r0 + rt * 16 + l4 * 4;
#pragma unroll
        for (int nt = 0; nt < 8; ++nt) {
            int col = wc * 128 + nt * 16 + l15;
            f32x4 c = acc[rt][nt];
#pragma unroll
            for (int r = 0; r < 4; ++r) {
                int row = rbase + r;
                if (row < N_NODES) xp1b[(size_t)row * D1 + col] = f2bf(c[r]);
            }
        }
    }
    // epilogue 2: fused al1s/al1d
#pragma unroll
    for (int hl = 0; hl < 4; ++hl) {
        int hg = wc * 4 + hl;
        float as0 = a1s[hg * NC + l15], as1 = a1s[hg * NC + 16 + l15];
        float ad0 = a1d[hg * NC + l15], ad1 = a1d[hg * NC + 16 + l15];
#pragma unroll
        for (int rt = 0; rt < 2; ++rt) {
            f32x4 c0 = acc[rt][2 * hl], c1 = acc[rt][2 * hl + 1];
#pragma unroll
            for (int r = 0; r < 4; ++r) {
                float ss = c0[r] * as0 + c1[r] * as1;
                float dd = c0[r] * ad0 + c1[r] * ad1;
#pragma unroll
                for (int msk = 1; msk < 16; msk <<= 1) {
                    ss += __shfl_xor(ss, msk);
                    dd += __shfl_xor(dd, msk);
                }
                int row = r0 + rt * 16 + l4 * 4 + r;
                if (l15 == 0 && row < N_NODES) {
                    al1s[row * NH + hg] = ss;
                    al1d[row * NH + hg] = dd;
                }
            }
        }
    }
}

// ---------------- CSR build (edge histogram only) -----------------------------
__global__ void k_hist(const int* __restrict__ ei, int* __restrict__ cnt) {
    int e = blockIdx.x * blockDim.x + threadIdx.x;
    if (e >= N_EDGES) return;
    atomicAdd(&cnt[ei[N_EDGES + e]], 1);
}

__global__ void k_scan1(const int* __restrict__ cnt, int* __restrict__ rowptr,
                        int* __restrict__ bsums) {
    __shared__ int sh[256];
    int i = blockIdx.x * 256 + threadIdx.x;
    int v = (i < N_NODES) ? cnt[i] : 0;
    sh[threadIdx.x] = v;
    __syncthreads();
    for (int d = 1; d < 256; d <<= 1) {
        int t = (threadIdx.x >= d) ? sh[threadIdx.x - d] : 0;
        __syncthreads();
        sh[threadIdx.x] += t;
        __syncthreads();
    }
    if (i < N_NODES) rowptr[i] = sh[threadIdx.x] - v;   // exclusive
    if (threadIdx.x == 255) bsums[blockIdx.x] = sh[255];
}

// scan2 folded in: every block redundantly scans the 196 block sums
__global__ void k_scan3(int* __restrict__ rowptr, const int* __restrict__ bsums,
                        int* __restrict__ cursor) {
    __shared__ int sh[256];
    int t = threadIdx.x;
    int v = (t < NB_N) ? bsums[t] : 0;
    sh[t] = v;
    __syncthreads();
    for (int d = 1; d < 256; d <<= 1) {
        int tv = (t >= d) ? sh[t - d] : 0;
        __syncthreads();
        sh[t] += tv;
        __syncthreads();
    }
    int prefix = (blockIdx.x == 0) ? 0 : sh[blockIdx.x - 1];
    int i = blockIdx.x * 256 + t;
    if (i < N_NODES) {
        int r = rowptr[i] + prefix;
        rowptr[i] = r;
        cursor[i] = r;
    }
}

__global__ void k_scatter(const int* __restrict__ ei, int* __restrict__ cursor,
                          int* __restrict__ esrc) {
    int e = blockIdx.x * blockDim.x + threadIdx.x;
    if (e >= E_TOT) return;
    int s, d;
    if (e < N_EDGES) { s = ei[e]; d = ei[N_EDGES + e]; }
    else { s = d = e - N_EDGES; }
    int pos = atomicAdd(&cursor[d], 1);
    esrc[pos] = s;
}

// ------- attention layer 1 (wave per dst) + FUSED GEMM2/al2 epilogue ----------
__global__ __launch_bounds__(256) void k_att1f(
    const unsigned short* __restrict__ xp1b, const float* __restrict__ al1s,
    const float* __restrict__ al1d, const float* __restrict__ b1,
    const float* __restrict__ W2, const float* __restrict__ a2s,
    const float* __restrict__ a2d, const int* __restrict__ rowptr,
    const int* __restrict__ cnt, const int* __restrict__ esrc,
    float* __restrict__ xp2, float* __restrict__ al2s, float* __restrict__ al2d) {
    __shared__ float s_w2[D1 * NCLS];      // 16 KB
    __shared__ int s_src[4][64];
    __shared__ float s_alpha[4][64 * 8];
    for (int i = threadIdx.x; i < (D1 * NCLS) / 4; i += 256)
        ((float4*)s_w2)[i] = ((const float4*)W2)[i];
    __syncthreads();

    int wv = threadIdx.x >> 6;
    int lane = threadIdx.x & 63;
    int n = blockIdx.x * 4 + wv;          // grid exactly covers 50000 = 12500*4
    int start = rowptr[n];
    int deg = cnt[n];
    int dcap = deg < 64 ? deg : 64;
    for (int j = lane; j < dcap; j += 64) s_src[wv][j] = esrc[start + j];
    // pass 1: online softmax stats, 8 edges x 8 heads; stash v in LDS
    int h = lane & 7, eg = lane >> 3;
    float ald = al1d[n * NH + h];
    float m = -1e30f, den = 0.f;
    for (int j = eg; j < dcap; j += 8) {
        int s = s_src[wv][j];
        float v = al1s[s * NH + h] + ald;
        v = v > 0.f ? v : NEG * v;
        s_alpha[wv][j * 8 + h] = v;
        if (v > m) { den = den * __expf(m - v) + 1.f; m = v; }
        else den += __expf(v - m);
    }
    for (int j = 64 + eg; j < deg; j += 8) {      // rare tail
        int s = esrc[start + j];
        float v = al1s[s * NH + h] + ald;
        v = v > 0.f ? v : NEG * v;
        if (v > m) { den = den * __expf(m - v) + 1.f; m = v; }
        else den += __expf(v - m);
    }
    for (int msk = 8; msk < 64; msk <<= 1) {
        float mo = __shfl_xor(m, msk), dn = __shfl_xor(den, msk);
        float nm = fmaxf(m, mo);
        den = den * __expf(m - nm) + dn * __expf(mo - nm);
        m = nm;
    }
    float rden1 = 1.f / den;
    // pass 1.5: v -> alpha in LDS (no re-gather)
    for (int j = eg; j < dcap; j += 8) {
        float v = s_alpha[wv][j * 8 + h];
        s_alpha[wv][j * 8 + h] = __expf(v - m) * rden1;
    }
    // pass 2: pure alpha*gather-fma, 4 gathers in flight per half-wave
    int eh = lane >> 5;
    int l5 = lane & 31;
    int h2 = l5 >> 2;
    float m2 = __shfl(m, h2);
    float rd2 = __shfl(rden1, h2);
    float ald2 = al1d[n * NH + h2];
    const int cb = l5 << 3;
    float acc[8] = {0.f, 0.f, 0.f, 0.f, 0.f, 0.f, 0.f, 0.f};
    for (int j0 = 0; j0 < dcap; j0 += 8) {
        const unsigned short* p[4];
        float a[4];
#pragma unroll
        for (int k = 0; k < 4; ++k) {
            int e = j0 + eh + 2 * k;
            bool act = e < dcap;
            int ee = act ? e : 0;
            int s = s_src[wv][ee];
            a[k] = act ? s_alpha[wv][ee * 8 + h2] : 0.f;
            p[k] = xp1b + (size_t)s * D1 + cb;
        }
#pragma unroll
        for (int k = 0; k < 4; ++k) {
            u16x8 xv = *(const u16x8*)p[k];
#pragma unroll
            for (int c = 0; c < 8; ++c) acc[c] = fmaf(a[k], bf2f(xv[c]), acc[c]);
        }
    }
    for (int j = 64 + eh; j < deg; j += 2) {      // rare tail
        int s = esrc[start + j];
        float v = al1s[s * NH + h2] + ald2;
        v = v > 0.f ? v : NEG * v;
        float al = __expf(v - m2) * rd2;
        u16x8 xv = *(const u16x8*)(xp1b + (size_t)s * D1 + cb);
#pragma unroll
        for (int c = 0; c < 8; ++c) acc[c] = fmaf(al, bf2f(xv[c]), acc[c]);
    }
#pragma unroll
    for (int c = 0; c < 8; ++c) acc[c] += __shfl_xor(acc[c], 32);
    // h1 row (fp32): all lanes hold channels cb..cb+7
    float hv[8];
#pragma unroll
    for (int c = 0; c < 8; ++c) {
        float av = acc[c] + b1[cb + c];
        hv[c] = av > 0.f ? av : expm1f(av);   // ELU fused
    }
    // fused GEMM2: this lane's partial for outputs o = eh*8 .. eh*8+7
    float po[8] = {0.f, 0.f, 0.f, 0.f, 0.f, 0.f, 0.f, 0.f};
#pragma unroll
    for (int c = 0; c < 8; ++c) {
        const float* wrow = &s_w2[(cb + c) * NCLS + eh * 8];
        float4 w0 = *(const float4*)(wrow);
        float4 w1 = *(const float4*)(wrow + 4);
        float hh = hv[c];
        po[0] = fmaf(hh, w0.x, po[0]); po[1] = fmaf(hh, w0.y, po[1]);
        po[2] = fmaf(hh, w0.z, po[2]); po[3] = fmaf(hh, w0.w, po[3]);
        po[4] = fmaf(hh, w1.x, po[4]); po[5] = fmaf(hh, w1.y, po[5]);
        po[6] = fmaf(hh, w1.z, po[6]); po[7] = fmaf(hh, w1.w, po[7]);
    }
#pragma unroll
    for (int o = 0; o < 8; ++o) {
#pragma unroll
        for (int msk = 1; msk < 32; msk <<= 1) po[o] += __shfl_xor(po[o], msk);
    }
    // al2 logits (fused)
    float ss, dd;
    {
        float4 as0 = *(const float4*)(a2s + eh * 8);
        float4 as1 = *(const float4*)(a2s + eh * 8 + 4);
        float4 ad0 = *(const float4*)(a2d + eh * 8);
        float4 ad1 = *(const float4*)(a2d + eh * 8 + 4);
        ss = po[0]*as0.x + po[1]*as0.y + po[2]*as0.z + po[3]*as0.w
           + po[4]*as1.x + po[5]*as1.y + po[6]*as1.z + po[7]*as1.w;
        dd = po[0]*ad0.x + po[1]*ad0.y + po[2]*ad0.z + po[3]*ad0.w
           + po[4]*ad1.x + po[5]*ad1.y + po[6]*ad1.z + po[7]*ad1.w;
    }
    ss += __shfl_xor(ss, 32);
    dd += __shfl_xor(dd, 32);
    if (l5 == 0) {
        float4 o0 = {po[0], po[1], po[2], po[3]};
        float4 o1 = {po[4], po[5], po[6], po[7]};
        *(float4*)(xp2 + (size_t)n * NCLS + eh * 8) = o0;
        *(float4*)(xp2 + (size_t)n * NCLS + eh * 8 + 4) = o1;
        if (eh == 0) { al2s[n] = ss; al2d[n] = dd; }
    }
}

// ---------------- attention layer 2 (wave per dst node) -----------------------
__global__ __launch_bounds__(256) void k_att2(
    const float* __restrict__ xp2, const float* __restrict__ al2s,
    const float* __restrict__ al2d, const float* __restrict__ b2,
    const int* __restrict__ rowptr, const int* __restrict__ cnt,
    const int* __restrict__ esrc, float* __restrict__ out2) {
    __shared__ int s_src[4][64];
    __shared__ float s_a[4][64];
    int wave = threadIdx.x >> 6;
    int lane = threadIdx.x & 63;
    int n = blockIdx.x * 4 + wave;
    int start = rowptr[n];
    int deg = cnt[n];
    int dcap = deg < 64 ? deg : 64;
    float ald = al2d[n];
    float m = -1e30f, den = 0.f;
    for (int j = lane; j < dcap; j += 64) {
        int s = esrc[start + j];
        s_src[wave][j] = s;
        float v = al2s[s] + ald;
        v = v > 0.f ? v : NEG * v;
        s_a[wave][j] = v;
        if (v > m) { den = den * __expf(m - v) + 1.f; m = v; }
        else den += __expf(v - m);
    }
    for (int j = 64 + lane; j < deg; j += 64) {   // rare tail
        float v = al2s[esrc[start + j]] + ald;
        v = v > 0.f ? v : NEG * v;
        if (v > m) { den = den * __expf(m - v) + 1.f; m = v; }
        else den += __expf(v - m);
    }
    for (int msk = 1; msk < 64; msk <<= 1) {
        float mo = __shfl_xor(m, msk), dn = __shfl_xor(den, msk);
        float nm = fmaxf(m, mo);
        den = den * __expf(m - nm) + dn * __expf(mo - nm);
        m = nm;
    }
    float rden = 1.f / den;
    for (int j = lane; j < dcap; j += 64)
        s_a[wave][j] = __expf(s_a[wave][j] - m) * rden;
    int c = lane & 15;
    int eg = lane >> 4;                   // 4 edges x 16 channels
    float acc = 0.f;
    for (int j = eg; j < dcap; j += 4)
        acc += s_a[wave][j] * xp2[(size_t)s_src[wave][j] * NCLS + c];
    for (int j = 64 + eg; j < deg; j += 4) {      // rare tail
        int s = esrc[start + j];
        float v = al2s[s] + ald;
        v = v > 0.f ? v : NEG * v;
        acc += __expf(v - m) * rden * xp2[(size_t)s * NCLS + c];
    }
    acc += __shfl_xor(acc, 16);
    acc += __shfl_xor(acc, 32);
    if (lane < 16) out2[(size_t)n * NCLS + lane] = acc + b2[lane];
}

// ---------------- pooling (LDS pre-aggregation, sorted batch) -----------------
__global__ __launch_bounds__(256) void k_pool(
    const float* __restrict__ out2, const int* __restrict__ batch,
    float* __restrict__ poolS, float* __restrict__ poolC) {
    __shared__ float sacc[NGRP * NCLS];
    __shared__ float scnt[NGRP];
    for (int i = threadIdx.x; i < NGRP * NCLS; i += 256) sacc[i] = 0.f;
    if (threadIdx.x < NGRP) scnt[threadIdx.x] = 0.f;
    __syncthreads();
    int n = blockIdx.x * 256 + threadIdx.x;
    if (n < N_NODES) {
        int g = batch[n];
        atomicAdd(&scnt[g], 1.f);
#pragma unroll
        for (int cc = 0; cc < NCLS; ++cc)
            atomicAdd(&sacc[g * NCLS + cc], out2[(size_t)n * NCLS + cc]);
    }
    __syncthreads();
    for (int i = threadIdx.x; i < NGRP * NCLS; i += 256)
        if (sacc[i] != 0.f) atomicAdd(&poolS[i], sacc[i]);
    if (threadIdx.x < NGRP && scnt[threadIdx.x] != 0.f)
        atomicAdd(&poolC[threadIdx.x], scnt[threadIdx.x]);
}

__global__ void k_final(const float* __restrict__ poolS,
                        const float* __restrict__ poolC, float* __restrict__ out) {
    int g = threadIdx.x;
    if (g >= NGRP) return;
    float inv = 1.f / fmaxf(poolC[g], 1.f);
    float v[NCLS];
    float m = -1e30f;
#pragma unroll
    for (int c = 0; c < NCLS; ++c) {
        v[c] = poolS[g * NCLS + c] * inv;
        m = fmaxf(m, v[c]);
    }
    float s = 0.f;
#pragma unroll
    for (int c = 0; c < NCLS; ++c) s += expf(v[c] - m);
    float lse = m + logf(s);
#pragma unroll
    for (int c = 0; c < NCLS; ++c) out[g * NCLS + c] = v[c] - lse;
}

extern "C" void kernel_launch(void* const* d_in, const int* in_sizes, int n_in,
                              void* d_out, int out_size, void* d_ws, size_t ws_size,
                              hipStream_t stream) {
    const float* x    = (const float*)d_in[0];
    const int*   ei   = (const int*)d_in[1];
    const int*   batch = (const int*)d_in[2];
    const float* W1   = (const float*)d_in[3];
    const float* a1s  = (const float*)d_in[4];
    const float* a1d  = (const float*)d_in[5];
    const float* b1   = (const float*)d_in[6];
    const float* W2   = (const float*)d_in[7];
    const float* a2s  = (const float*)d_in[8];
    const float* a2d  = (const float*)d_in[9];
    const float* b2   = (const float*)d_in[10];
    float* out = (float*)d_out;

    float* f = (float*)d_ws;
    float* al1s_ = f;  f += (size_t)N_NODES * NH;
    float* al1d_ = f;  f += (size_t)N_NODES * NH;
    float* xp2   = f;  f += (size_t)N_NODES * NCLS;
    float* al2s_ = f;  f += N_NODES;
    float* al2d_ = f;  f += N_NODES;
    float* out2  = f;  f += (size_t)N_NODES * NCLS;
    float* poolS = f;  f += NGRP * NCLS;
    float* poolC = f;  f += NGRP;
    unsigned short* xp1b = (unsigned short*)f;
    unsigned short* w1p  = xp1b + (size_t)N_NODES * D1;
    int* cnt    = (int*)(w1p + FDIM * D1);
    int* rowptr = cnt + N_NODES;
    int* cursor = rowptr + N_NODES;
    int* esrc   = cursor + N_NODES;
    int* bsums  = esrc + E_TOT;

    k_init<<<NB_N, 256, 0, stream>>>(W1, w1p, cnt, poolS, poolC);
    k_gemm1m<<<(N_NODES + 63) / 64, 256, 0, stream>>>(x, w1p, a1s, a1d, xp1b, al1s_, al1d_);
    k_hist<<<(N_EDGES + 255) / 256, 256, 0, stream>>>(ei, cnt);
    k_scan1<<<NB_N, 256, 0, stream>>>(cnt, rowptr, bsums);
    k_scan3<<<NB_N, 256, 0, stream>>>(rowptr, bsums, cursor);
    k_scatter<<<(E_TOT + 255) / 256, 256, 0, stream>>>(ei, cursor, esrc);
    k_att1f<<<N_NODES / 4, 256, 0, stream>>>(xp1b, al1s_, al1d_, b1, W2, a2s, a2d,
                                             rowptr, cnt, esrc, xp2, al2s_, al2d_);
    k_att2<<<N_NODES / 4, 256, 0, stream>>>(xp2, al2s_, al2d_, b2, rowptr, cnt, esrc, out2);
    k_pool<<<NB_N, 256, 0, stream>>>(out2, batch, poolS, poolC);
    k_final<<<1, 64, 0, stream>>>(poolS, poolC, out);
}

// Round 7
// 257.877 us; speedup vs baseline: 1.3713x; 1.3713x over previous
//
#include <hip/hip_runtime.h>
#include <math.h>

#define N_NODES 50000
#define N_EDGES 800000
#define FDIM 128
#define NH 8
#define NC 32
#define D1 256      // NH*NC
#define NCLS 16
#define NGRP 64
#define NEG 0.2f
#define E_TOT (N_EDGES + N_NODES)
#define NB_N 196    // (N_NODES+255)/256
#define G1_BLOCKS 782  // (N_NODES+63)/64

typedef __attribute__((ext_vector_type(8))) unsigned short u16x8;
typedef __attribute__((ext_vector_type(4))) unsigned short u16x4;
typedef __attribute__((ext_vector_type(8))) short short8;
typedef __attribute__((ext_vector_type(4))) float f32x4;

static __device__ __forceinline__ float bf2f(unsigned short u) {
    return __uint_as_float(((unsigned int)u) << 16);
}
static __device__ __forceinline__ unsigned short f2bf(float f) {
    unsigned int b = __float_as_uint(f);
    return (unsigned short)((b + 0x7FFFu + ((b >> 16) & 1u)) >> 16);
}

// ------ init: cnt=1, pool accums=0, W1 -> per-lane-packed bf16 B fragments ----
__global__ void k_init(const float* __restrict__ W1, unsigned short* __restrict__ w1p,
                       int* __restrict__ cnt, float* __restrict__ poolS,
                       float* __restrict__ poolC) {
    int i = blockIdx.x * 256 + threadIdx.x;
    if (i < N_NODES) cnt[i] = 1;               // self loop
    if (i < NGRP * NCLS) poolS[i] = 0.f;
    if (i < NGRP) poolC[i] = 0.f;
    if (i < FDIM * D1) {
        int ks = i >> 13;
        int r = i & 8191;
        int nt2 = r >> 9;
        int r2 = r & 511;
        int lane = r2 >> 3, e = r2 & 7;
        int k = ks * 32 + (lane >> 4) * 8 + e;
        int col = nt2 * 16 + (lane & 15);
        w1p[i] = f2bf(W1[k * D1 + col]);
    }
}

// --- GEMM1 via MFMA bf16 (no LDS) + fused al1 + fused edge histogram ---------
__global__ __launch_bounds__(256) void k_gemm1m(
    const float* __restrict__ x, const unsigned short* __restrict__ w1p,
    const float* __restrict__ a1s, const float* __restrict__ a1d,
    const int* __restrict__ ei, int* __restrict__ cnt,
    unsigned short* __restrict__ xp1b, float* __restrict__ al1s,
    float* __restrict__ al1d) {
    // fused histogram: fire-and-forget atomics, overlap with GEMM below
    for (int e = blockIdx.x * 256 + threadIdx.x; e < N_EDGES; e += G1_BLOCKS * 256)
        atomicAdd(&cnt[ei[N_EDGES + e]], 1);

    const int l = threadIdx.x & 63;
    const int wid = threadIdx.x >> 6;
    const int wr = wid >> 1, wc = wid & 1;
    const int l15 = l & 15, l4 = l >> 4;
    const int base = blockIdx.x * 64;
    const int r0 = base + wr * 32;

    f32x4 acc[2][8] = {};
#pragma unroll
    for (int ks = 0; ks < 4; ++ks) {
        const int kk = ks * 32 + l4 * 8;
        short8 af[2];
#pragma unroll
        for (int rt = 0; rt < 2; ++rt) {
            int row = r0 + rt * 16 + l15;
            float4 v0 = make_float4(0.f, 0.f, 0.f, 0.f), v1 = v0;
            if (row < N_NODES) {
                const float* xr = x + (size_t)row * FDIM + kk;
                v0 = *(const float4*)xr;
                v1 = *(const float4*)(xr + 4);
            }
            short8 a;
            a[0] = (short)f2bf(v0.x); a[1] = (short)f2bf(v0.y);
            a[2] = (short)f2bf(v0.z); a[3] = (short)f2bf(v0.w);
            a[4] = (short)f2bf(v1.x); a[5] = (short)f2bf(v1.y);
            a[6] = (short)f2bf(v1.z); a[7] = (short)f2bf(v1.w);
            af[rt] = a;
        }
#pragma unroll
        for (int nt = 0; nt < 8; ++nt) {
            int nt2 = wc * 8 + nt;
            short8 bf_ = *(const short8*)&w1p[(size_t)((ks * 16 + nt2) * 64 + l) * 8];
            acc[0][nt] = __builtin_amdgcn_mfma_f32_16x16x32_bf16(af[0], bf_, acc[0][nt], 0, 0, 0);
            acc[1][nt] = __builtin_amdgcn_mfma_f32_16x16x32_bf16(af[1], bf_, acc[1][nt], 0, 0, 0);
        }
    }
    // epilogue 1: bf16 stores (C/D: col=lane&15, row=(lane>>4)*4+reg)
#pragma unroll
    for (int rt = 0; rt < 2; ++rt) {
        int rbase = r0 + rt * 16 + l4 * 4;
#pragma unroll
        for (int nt = 0; nt < 8; ++nt) {
            int col = wc * 128 + nt * 16 + l15;
            f32x4 c = acc[rt][nt];
#pragma unroll
            for (int r = 0; r < 4; ++r) {
                int row = rbase + r;
                if (row < N_NODES) xp1b[(size_t)row * D1 + col] = f2bf(c[r]);
            }
        }
    }
    // epilogue 2: fused al1s/al1d
#pragma unroll
    for (int hl = 0; hl < 4; ++hl) {
        int hg = wc * 4 + hl;
        float as0 = a1s[hg * NC + l15], as1 = a1s[hg * NC + 16 + l15];
        float ad0 = a1d[hg * NC + l15], ad1 = a1d[hg * NC + 16 + l15];
#pragma unroll
        for (int rt = 0; rt < 2; ++rt) {
            f32x4 c0 = acc[rt][2 * hl], c1 = acc[rt][2 * hl + 1];
#pragma unroll
            for (int r = 0; r < 4; ++r) {
                float ss = c0[r] * as0 + c1[r] * as1;
                float dd = c0[r] * ad0 + c1[r] * ad1;
#pragma unroll
                for (int msk = 1; msk < 16; msk <<= 1) {
                    ss += __shfl_xor(ss, msk);
                    dd += __shfl_xor(dd, msk);
                }
                int row = r0 + rt * 16 + l4 * 4 + r;
                if (l15 == 0 && row < N_NODES) {
                    al1s[row * NH + hg] = ss;
                    al1d[row * NH + hg] = dd;
                }
            }
        }
    }
}

__global__ void k_scan1(const int* __restrict__ cnt, int* __restrict__ rowptr,
                        int* __restrict__ bsums) {
    __shared__ int sh[256];
    int i = blockIdx.x * 256 + threadIdx.x;
    int v = (i < N_NODES) ? cnt[i] : 0;
    sh[threadIdx.x] = v;
    __syncthreads();
    for (int d = 1; d < 256; d <<= 1) {
        int t = (threadIdx.x >= d) ? sh[threadIdx.x - d] : 0;
        __syncthreads();
        sh[threadIdx.x] += t;
        __syncthreads();
    }
    if (i < N_NODES) rowptr[i] = sh[threadIdx.x] - v;   // exclusive
    if (threadIdx.x == 255) bsums[blockIdx.x] = sh[255];
}

// scan2 folded in: every block redundantly scans the 196 block sums
__global__ void k_scan3(int* __restrict__ rowptr, const int* __restrict__ bsums,
                        int* __restrict__ cursor) {
    __shared__ int sh[256];
    int t = threadIdx.x;
    int v = (t < NB_N) ? bsums[t] : 0;
    sh[t] = v;
    __syncthreads();
    for (int d = 1; d < 256; d <<= 1) {
        int tv = (t >= d) ? sh[t - d] : 0;
        __syncthreads();
        sh[t] += tv;
        __syncthreads();
    }
    int prefix = (blockIdx.x == 0) ? 0 : sh[blockIdx.x - 1];
    int i = blockIdx.x * 256 + t;
    if (i < N_NODES) {
        int r = rowptr[i] + prefix;
        rowptr[i] = r;
        cursor[i] = r;
    }
}

__global__ void k_scatter(const int* __restrict__ ei, int* __restrict__ cursor,
                          int* __restrict__ esrc) {
    int e = blockIdx.x * blockDim.x + threadIdx.x;
    if (e >= E_TOT) return;
    int s, d;
    if (e < N_EDGES) { s = ei[e]; d = ei[N_EDGES + e]; }
    else { s = d = e - N_EDGES; }
    int pos = atomicAdd(&cursor[d], 1);
    esrc[pos] = s;
}

// ---------------- attention layer 1 (wave per dst node) -----------------------
__global__ __launch_bounds__(256) void k_att1(
    const unsigned short* __restrict__ xp1b, const float* __restrict__ al1s,
    const float* __restrict__ al1d, const float* __restrict__ b1,
    const int* __restrict__ rowptr, const int* __restrict__ cnt,
    const int* __restrict__ esrc, unsigned short* __restrict__ h1b) {
    __shared__ int s_src[4][64];
    __shared__ float s_alpha[4][64 * 8];
    int wv = threadIdx.x >> 6;
    int lane = threadIdx.x & 63;
    int n = blockIdx.x * 4 + wv;          // grid exactly covers 50000 = 12500*4
    int start = rowptr[n];
    int deg = cnt[n];
    int dcap = deg < 64 ? deg : 64;
    for (int j = lane; j < dcap; j += 64) s_src[wv][j] = esrc[start + j];
    // pass 1: online softmax stats, 8 edges x 8 heads; stash v in LDS
    int h = lane & 7, eg = lane >> 3;
    float ald = al1d[n * NH + h];
    float m = -1e30f, den = 0.f;
    for (int j = eg; j < dcap; j += 8) {
        int s = s_src[wv][j];
        float v = al1s[s * NH + h] + ald;
        v = v > 0.f ? v : NEG * v;
        s_alpha[wv][j * 8 + h] = v;
        if (v > m) { den = den * __expf(m - v) + 1.f; m = v; }
        else den += __expf(v - m);
    }
    for (int j = 64 + eg; j < deg; j += 8) {      // rare tail
        int s = esrc[start + j];
        float v = al1s[s * NH + h] + ald;
        v = v > 0.f ? v : NEG * v;
        if (v > m) { den = den * __expf(m - v) + 1.f; m = v; }
        else den += __expf(v - m);
    }
    for (int msk = 8; msk < 64; msk <<= 1) {
        float mo = __shfl_xor(m, msk), dn = __shfl_xor(den, msk);
        float nm = fmaxf(m, mo);
        den = den * __expf(m - nm) + dn * __expf(mo - nm);
        m = nm;
    }
    float rden1 = 1.f / den;
    // pass 1.5: v -> alpha in LDS (no re-gather)
    for (int j = eg; j < dcap; j += 8) {
        float v = s_alpha[wv][j * 8 + h];
        s_alpha[wv][j * 8 + h] = __expf(v - m) * rden1;
    }
    // pass 2: full-wave per edge; lane owns 4 channels; 8 edges in flight
    int hh = lane >> 3;                   // head of this lane's channels
    int cb = lane << 2;                   // channel base (lane*4)
    float m2 = __shfl(m, hh);
    float rd2 = __shfl(rden1, hh);
    float ald2 = al1d[n * NH + hh];
    float a0 = 0.f, a1 = 0.f, a2 = 0.f, a3 = 0.f;
    for (int j0 = 0; j0 < dcap; j0 += 8) {
        const unsigned short* p[8];
        float aw[8];
#pragma unroll
        for (int k = 0; k < 8; ++k) {
            int e = j0 + k;
            bool act = e < dcap;
            int ee = act ? e : 0;
            int s = s_src[wv][ee];
            aw[k] = act ? s_alpha[wv][ee * 8 + hh] : 0.f;
            p[k] = xp1b + (size_t)s * D1 + cb;
        }
#pragma unroll
        for (int k = 0; k < 8; ++k) {
            u16x4 xv = *(const u16x4*)p[k];
            a0 = fmaf(aw[k], bf2f(xv[0]), a0);
            a1 = fmaf(aw[k], bf2f(xv[1]), a1);
            a2 = fmaf(aw[k], bf2f(xv[2]), a2);
            a3 = fmaf(aw[k], bf2f(xv[3]), a3);
        }
    }
    for (int j = 64; j < deg; ++j) {      // rare tail
        int s = esrc[start + j];
        float v = al1s[s * NH + hh] + ald2;
        v = v > 0.f ? v : NEG * v;
        float al = __expf(v - m2) * rd2;
        u16x4 xv = *(const u16x4*)(xp1b + (size_t)s * D1 + cb);
        a0 = fmaf(al, bf2f(xv[0]), a0);
        a1 = fmaf(al, bf2f(xv[1]), a1);
        a2 = fmaf(al, bf2f(xv[2]), a2);
        a3 = fmaf(al, bf2f(xv[3]), a3);
    }
    // bias + ELU + bf16 store (no cross-lane reduce needed)
    float4 bb = *(const float4*)(b1 + cb);
    a0 += bb.x; a1 += bb.y; a2 += bb.z; a3 += bb.w;
    a0 = a0 > 0.f ? a0 : expm1f(a0);
    a1 = a1 > 0.f ? a1 : expm1f(a1);
    a2 = a2 > 0.f ? a2 : expm1f(a2);
    a3 = a3 > 0.f ? a3 : expm1f(a3);
    u16x4 pk = { f2bf(a0), f2bf(a1), f2bf(a2), f2bf(a3) };
    *(u16x4*)(h1b + (size_t)n * D1 + cb) = pk;
}

// ---------------- GEMM2 (bf16 h1 in, broadcast W2) + al2 epilogue -------------
__global__ __launch_bounds__(256) void k_gemm2(
    const unsigned short* __restrict__ h1b, const float* __restrict__ W2,
    const float* __restrict__ a2s, const float* __restrict__ a2d,
    float* __restrict__ xp2, float* __restrict__ al2s, float* __restrict__ al2d) {
    __shared__ float w2s[D1 * NCLS];
    for (int i = threadIdx.x; i < D1 * NCLS; i += 256) w2s[i] = W2[i];
    __syncthreads();
    int n = blockIdx.x * 256 + threadIdx.x;
    if (n >= N_NODES) return;
    float4 acc[4];
#pragma unroll
    for (int q = 0; q < 4; ++q) acc[q] = make_float4(0.f, 0.f, 0.f, 0.f);
    const unsigned short* hr = h1b + (size_t)n * D1;
    for (int k0 = 0; k0 < D1; k0 += 8) {
        u16x8 hv = *(const u16x8*)(hr + k0);
#pragma unroll
        for (int j = 0; j < 8; ++j) {
            float hx = bf2f(hv[j]);
#pragma unroll
            for (int q = 0; q < 4; ++q) {
                float4 w = *(const float4*)(&w2s[(k0 + j) * NCLS + q * 4]);
                acc[q].x = fmaf(hx, w.x, acc[q].x);
                acc[q].y = fmaf(hx, w.y, acc[q].y);
                acc[q].z = fmaf(hx, w.z, acc[q].z);
                acc[q].w = fmaf(hx, w.w, acc[q].w);
            }
        }
    }
    float ss = 0.f, dd = 0.f;
#pragma unroll
    for (int q = 0; q < 4; ++q) {
        *(float4*)(xp2 + (size_t)n * NCLS + q * 4) = acc[q];
        float4 s4 = *(const float4*)(a2s + q * 4);
        float4 d4 = *(const float4*)(a2d + q * 4);
        ss += acc[q].x * s4.x + acc[q].y * s4.y + acc[q].z * s4.z + acc[q].w * s4.w;
        dd += acc[q].x * d4.x + acc[q].y * d4.y + acc[q].z * d4.z + acc[q].w * d4.w;
    }
    al2s[n] = ss;
    al2d[n] = dd;
}

// ---------------- attention layer 2 (wave per dst node) -----------------------
__global__ __launch_bounds__(256) void k_att2(
    const float* __restrict__ xp2, const float* __restrict__ al2s,
    const float* __restrict__ al2d, const float* __restrict__ b2,
    const int* __restrict__ rowptr, const int* __restrict__ cnt,
    const int* __restrict__ esrc, float* __restrict__ out2) {
    __shared__ int s_src[4][64];
    __shared__ float s_a[4][64];
    int wave = threadIdx.x >> 6;
    int lane = threadIdx.x & 63;
    int n = blockIdx.x * 4 + wave;
    int start = rowptr[n];
    int deg = cnt[n];
    int dcap = deg < 64 ? deg : 64;
    float ald = al2d[n];
    float m = -1e30f, den = 0.f;
    for (int j = lane; j < dcap; j += 64) {
        int s = esrc[start + j];
        s_src[wave][j] = s;
        float v = al2s[s] + ald;
        v = v > 0.f ? v : NEG * v;
        s_a[wave][j] = v;
        if (v > m) { den = den * __expf(m - v) + 1.f; m = v; }
        else den += __expf(v - m);
    }
    for (int j = 64 + lane; j < deg; j += 64) {   // rare tail
        float v = al2s[esrc[start + j]] + ald;
        v = v > 0.f ? v : NEG * v;
        if (v > m) { den = den * __expf(m - v) + 1.f; m = v; }
        else den += __expf(v - m);
    }
    for (int msk = 1; msk < 64; msk <<= 1) {
        float mo = __shfl_xor(m, msk), dn = __shfl_xor(den, msk);
        float nm = fmaxf(m, mo);
        den = den * __expf(m - nm) + dn * __expf(mo - nm);
        m = nm;
    }
    float rden = 1.f / den;
    for (int j = lane; j < dcap; j += 64)
        s_a[wave][j] = __expf(s_a[wave][j] - m) * rden;
    int c = lane & 15;
    int eg = lane >> 4;                   // 4 edges x 16 channels
    float acc = 0.f;
    for (int j = eg; j < dcap; j += 4)
        acc += s_a[wave][j] * xp2[(size_t)s_src[wave][j] * NCLS + c];
    for (int j = 64 + eg; j < deg; j += 4) {      // rare tail
        int s = esrc[start + j];
        float v = al2s[s] + ald;
        v = v > 0.f ? v : NEG * v;
        acc += __expf(v - m) * rden * xp2[(size_t)s * NCLS + c];
    }
    acc += __shfl_xor(acc, 16);
    acc += __shfl_xor(acc, 32);
    if (lane < 16) out2[(size_t)n * NCLS + lane] = acc + b2[lane];
}

// ---------------- pooling (LDS pre-aggregation, sorted batch) -----------------
__global__ __launch_bounds__(256) void k_pool(
    const float* __restrict__ out2, const int* __restrict__ batch,
    float* __restrict__ poolS, float* __restrict__ poolC) {
    __shared__ float sacc[NGRP * NCLS];
    __shared__ float scnt[NGRP];
    for (int i = threadIdx.x; i < NGRP * NCLS; i += 256) sacc[i] = 0.f;
    if (threadIdx.x < NGRP) scnt[threadIdx.x] = 0.f;
    __syncthreads();
    int n = blockIdx.x * 256 + threadIdx.x;
    if (n < N_NODES) {
        int g = batch[n];
        atomicAdd(&scnt[g], 1.f);
#pragma unroll
        for (int cc = 0; cc < NCLS; ++cc)
            atomicAdd(&sacc[g * NCLS + cc], out2[(size_t)n * NCLS + cc]);
    }
    __syncthreads();
    for (int i = threadIdx.x; i < NGRP * NCLS; i += 256)
        if (sacc[i] != 0.f) atomicAdd(&poolS[i], sacc[i]);
    if (threadIdx.x < NGRP && scnt[threadIdx.x] != 0.f)
        atomicAdd(&poolC[threadIdx.x], scnt[threadIdx.x]);
}

__global__ void k_final(const float* __restrict__ poolS,
                        const float* __restrict__ poolC, float* __restrict__ out) {
    int g = threadIdx.x;
    if (g >= NGRP) return;
    float inv = 1.f / fmaxf(poolC[g], 1.f);
    float v[NCLS];
    float m = -1e30f;
#pragma unroll
    for (int c = 0; c < NCLS; ++c) {
        v[c] = poolS[g * NCLS + c] * inv;
        m = fmaxf(m, v[c]);
    }
    float s = 0.f;
#pragma unroll
    for (int c = 0; c < NCLS; ++c) s += expf(v[c] - m);
    float lse = m + logf(s);
#pragma unroll
    for (int c = 0; c < NCLS; ++c) out[g * NCLS + c] = v[c] - lse;
}

extern "C" void kernel_launch(void* const* d_in, const int* in_sizes, int n_in,
                              void* d_out, int out_size, void* d_ws, size_t ws_size,
                              hipStream_t stream) {
    const float* x    = (const float*)d_in[0];
    const int*   ei   = (const int*)d_in[1];
    const int*   batch = (const int*)d_in[2];
    const float* W1   = (const float*)d_in[3];
    const float* a1s  = (const float*)d_in[4];
    const float* a1d  = (const float*)d_in[5];
    const float* b1   = (const float*)d_in[6];
    const float* W2   = (const float*)d_in[7];
    const float* a2s  = (const float*)d_in[8];
    const float* a2d  = (const float*)d_in[9];
    const float* b2   = (const float*)d_in[10];
    float* out = (float*)d_out;

    float* f = (float*)d_ws;
    float* al1s_ = f;  f += (size_t)N_NODES * NH;
    float* al1d_ = f;  f += (size_t)N_NODES * NH;
    float* xp2   = f;  f += (size_t)N_NODES * NCLS;
    float* al2s_ = f;  f += N_NODES;
    float* al2d_ = f;  f += N_NODES;
    float* out2  = f;  f += (size_t)N_NODES * NCLS;
    float* poolS = f;  f += NGRP * NCLS;
    float* poolC = f;  f += NGRP;
    unsigned short* xp1b = (unsigned short*)f;
    unsigned short* h1b  = xp1b + (size_t)N_NODES * D1;
    unsigned short* w1p  = h1b + (size_t)N_NODES * D1;
    int* cnt    = (int*)(w1p + FDIM * D1);
    int* rowptr = cnt + N_NODES;
    int* cursor = rowptr + N_NODES;
    int* esrc   = cursor + N_NODES;
    int* bsums  = esrc + E_TOT;

    k_init<<<NB_N, 256, 0, stream>>>(W1, w1p, cnt, poolS, poolC);
    k_gemm1m<<<G1_BLOCKS, 256, 0, stream>>>(x, w1p, a1s, a1d, ei, cnt, xp1b, al1s_, al1d_);
    k_scan1<<<NB_N, 256, 0, stream>>>(cnt, rowptr, bsums);
    k_scan3<<<NB_N, 256, 0, stream>>>(rowptr, bsums, cursor);
    k_scatter<<<(E_TOT + 255) / 256, 256, 0, stream>>>(ei, cursor, esrc);
    k_att1<<<N_NODES / 4, 256, 0, stream>>>(xp1b, al1s_, al1d_, b1, rowptr, cnt, esrc, h1b);
    k_gemm2<<<NB_N, 256, 0, stream>>>(h1b, W2, a2s, a2d, xp2, al2s_, al2d_);
    k_att2<<<N_NODES / 4, 256, 0, stream>>>(xp2, al2s_, al2d_, b2, rowptr, cnt, esrc, out2);
    k_pool<<<NB_N, 256, 0, stream>>>(out2, batch, poolS, poolC);
    k_final<<<1, 64, 0, stream>>>(poolS, poolC, out);
}

// Round 8
// 251.176 us; speedup vs baseline: 1.4079x; 1.0267x over previous
//
#include <hip/hip_runtime.h>
#include <math.h>

#define N_NODES 50000
#define N_EDGES 800000
#define FDIM 128
#define NH 8
#define NC 32
#define D1 256      // NH*NC
#define NCLS 16
#define NGRP 64
#define NEG 0.2f
#define E_TOT (N_EDGES + N_NODES)
#define NB_N 196        // (N_NODES+255)/256
#define G1_BLOCKS 782   // (N_NODES+63)/64
#define E_CHUNK 4096
#define NCHUNK 196      // ceil(800000/4096)
#define NBIN 196        // ceil(50000/256)

typedef __attribute__((ext_vector_type(8))) unsigned short u16x8;
typedef __attribute__((ext_vector_type(4))) unsigned short u16x4;
typedef __attribute__((ext_vector_type(8))) short short8;
typedef __attribute__((ext_vector_type(4))) float f32x4;

static __device__ __forceinline__ float bf2f(unsigned short u) {
    return __uint_as_float(((unsigned int)u) << 16);
}
static __device__ __forceinline__ unsigned short f2bf(float f) {
    unsigned int b = __float_as_uint(f);
    return (unsigned short)((b + 0x7FFFu + ((b >> 16) & 1u)) >> 16);
}

// ------ init: pool accums=0, W1 -> per-lane-packed bf16 B fragments -----------
__global__ void k_init(const float* __restrict__ W1, unsigned short* __restrict__ w1p,
                       float* __restrict__ poolS, float* __restrict__ poolC) {
    int i = blockIdx.x * 256 + threadIdx.x;
    if (i < NGRP * NCLS) poolS[i] = 0.f;
    if (i < NGRP) poolC[i] = 0.f;
    if (i < FDIM * D1) {
        int ks = i >> 13;
        int r = i & 8191;
        int nt2 = r >> 9;
        int r2 = r & 511;
        int lane = r2 >> 3, e = r2 & 7;
        int k = ks * 32 + (lane >> 4) * 8 + e;
        int col = nt2 * 16 + (lane & 15);
        w1p[i] = f2bf(W1[k * D1 + col]);
    }
}

// ------ GEMM1 via MFMA bf16 (no LDS): xp1b = bf16(x)@bf16(W1), fused al1 ------
__global__ __launch_bounds__(256) void k_gemm1m(
    const float* __restrict__ x, const unsigned short* __restrict__ w1p,
    const float* __restrict__ a1s, const float* __restrict__ a1d,
    unsigned short* __restrict__ xp1b, float* __restrict__ al1s,
    float* __restrict__ al1d) {
    const int l = threadIdx.x & 63;
    const int wid = threadIdx.x >> 6;
    const int wr = wid >> 1, wc = wid & 1;
    const int l15 = l & 15, l4 = l >> 4;
    const int base = blockIdx.x * 64;
    const int r0 = base + wr * 32;

    f32x4 acc[2][8] = {};
#pragma unroll
    for (int ks = 0; ks < 4; ++ks) {
        const int kk = ks * 32 + l4 * 8;
        short8 af[2];
#pragma unroll
        for (int rt = 0; rt < 2; ++rt) {
            int row = r0 + rt * 16 + l15;
            float4 v0 = make_float4(0.f, 0.f, 0.f, 0.f), v1 = v0;
            if (row < N_NODES) {
                const float* xr = x + (size_t)row * FDIM + kk;
                v0 = *(const float4*)xr;
                v1 = *(const float4*)(xr + 4);
            }
            short8 a;
            a[0] = (short)f2bf(v0.x); a[1] = (short)f2bf(v0.y);
            a[2] = (short)f2bf(v0.z); a[3] = (short)f2bf(v0.w);
            a[4] = (short)f2bf(v1.x); a[5] = (short)f2bf(v1.y);
            a[6] = (short)f2bf(v1.z); a[7] = (short)f2bf(v1.w);
            af[rt] = a;
        }
#pragma unroll
        for (int nt = 0; nt < 8; ++nt) {
            int nt2 = wc * 8 + nt;
            short8 bf_ = *(const short8*)&w1p[(size_t)((ks * 16 + nt2) * 64 + l) * 8];
            acc[0][nt] = __builtin_amdgcn_mfma_f32_16x16x32_bf16(af[0], bf_, acc[0][nt], 0, 0, 0);
            acc[1][nt] = __builtin_amdgcn_mfma_f32_16x16x32_bf16(af[1], bf_, acc[1][nt], 0, 0, 0);
        }
    }
#pragma unroll
    for (int rt = 0; rt < 2; ++rt) {
        int rbase = r0 + rt * 16 + l4 * 4;
#pragma unroll
        for (int nt = 0; nt < 8; ++nt) {
            int col = wc * 128 + nt * 16 + l15;
            f32x4 c = acc[rt][nt];
#pragma unroll
            for (int r = 0; r < 4; ++r) {
                int row = rbase + r;
                if (row < N_NODES) xp1b[(size_t)row * D1 + col] = f2bf(c[r]);
            }
        }
    }
#pragma unroll
    for (int hl = 0; hl < 4; ++hl) {
        int hg = wc * 4 + hl;
        float as0 = a1s[hg * NC + l15], as1 = a1s[hg * NC + 16 + l15];
        float ad0 = a1d[hg * NC + l15], ad1 = a1d[hg * NC + 16 + l15];
#pragma unroll
        for (int rt = 0; rt < 2; ++rt) {
            f32x4 c0 = acc[rt][2 * hl], c1 = acc[rt][2 * hl + 1];
#pragma unroll
            for (int r = 0; r < 4; ++r) {
                float ss = c0[r] * as0 + c1[r] * as1;
                float dd = c0[r] * ad0 + c1[r] * ad1;
#pragma unroll
                for (int msk = 1; msk < 16; msk <<= 1) {
                    ss += __shfl_xor(ss, msk);
                    dd += __shfl_xor(dd, msk);
                }
                int row = r0 + rt * 16 + l4 * 4 + r;
                if (l15 == 0 && row < N_NODES) {
                    al1s[row * NH + hg] = ss;
                    al1d[row * NH + hg] = dd;
                }
            }
        }
    }
}

// ---- CSR build, pass A: per-chunk LDS histogram of dst>>8 (no global atomics)
__global__ __launch_bounds__(256) void k_binhist(const int* __restrict__ ei,
                                                 int* __restrict__ binmat) {
    __shared__ int h[NBIN];
    int c = blockIdx.x;
    for (int b = threadIdx.x; b < NBIN; b += 256) h[b] = 0;
    __syncthreads();
    int e0 = c * E_CHUNK;
    int e1 = e0 + E_CHUNK; if (e1 > N_EDGES) e1 = N_EDGES;
    for (int e = e0 + threadIdx.x; e < e1; e += 256)
        atomicAdd(&h[ei[N_EDGES + e] >> 8], 1);
    __syncthreads();
    for (int b = threadIdx.x; b < NBIN; b += 256) binmat[b * NCHUNK + c] = h[b];
}

// ---- pass B: exclusive scan of binmat (bin-major), single 1024-thread block --
__global__ __launch_bounds__(1024) void k_binscan(int* __restrict__ binmat) {
    __shared__ int sh[1024];
    const int TOT = NBIN * NCHUNK;          // 38416
    const int PER = (TOT + 1023) / 1024;    // 38
    int t = threadIdx.x;
    int i0 = t * PER;
    int i1 = i0 + PER; if (i1 > TOT) i1 = TOT;
    int sum = 0;
    for (int i = i0; i < i1; ++i) sum += binmat[i];
    sh[t] = sum;
    __syncthreads();
    for (int d = 1; d < 1024; d <<= 1) {
        int v = (t >= d) ? sh[t - d] : 0;
        __syncthreads();
        sh[t] += v;
        __syncthreads();
    }
    int run = (t == 0) ? 0 : sh[t - 1];
    for (int i = i0; i < i1; ++i) {
        int v = binmat[i];
        binmat[i] = run;
        run += v;
    }
}

// ---- pass C: scatter edges to bin-grouped array via LDS cursors --------------
__global__ __launch_bounds__(256) void k_binscatter(const int* __restrict__ ei,
                                                    const int* __restrict__ offs,
                                                    int* __restrict__ binned) {
    __shared__ int cur[NBIN];
    int c = blockIdx.x;
    for (int b = threadIdx.x; b < NBIN; b += 256) cur[b] = offs[b * NCHUNK + c];
    __syncthreads();
    int e0 = c * E_CHUNK;
    int e1 = e0 + E_CHUNK; if (e1 > N_EDGES) e1 = N_EDGES;
    for (int e = e0 + threadIdx.x; e < e1; e += 256) {
        int s = ei[e], d = ei[N_EDGES + e];
        int pos = atomicAdd(&cur[d >> 8], 1);
        binned[pos] = s | ((d & 255) << 16);   // src < 65536
    }
}

// ---- pass D: per-bin CSR finalize (rowptr/cnt/esrc incl. self-loops) ---------
__global__ __launch_bounds__(256) void k_bincsr(const int* __restrict__ offs,
                                                const int* __restrict__ binned,
                                                int* __restrict__ rowptr,
                                                int* __restrict__ cnt,
                                                int* __restrict__ esrc) {
    __shared__ int lcnt[256];
    __shared__ int sh[256];
    __shared__ int lcur[256];
    int b = blockIdx.x;
    int t = threadIdx.x;
    int estart = offs[b * NCHUNK];
    int eend = (b == NBIN - 1) ? N_EDGES : offs[(b + 1) * NCHUNK];
    int nbase = b * 256;
    int nin = N_NODES - nbase; if (nin > 256) nin = 256;
    lcnt[t] = 0;
    __syncthreads();
    for (int e = estart + t; e < eend; e += 256)
        atomicAdd(&lcnt[(binned[e] >> 16) & 255], 1);
    __syncthreads();
    int myc = lcnt[t] + (t < nin ? 1 : 0);   // + self loop
    sh[t] = myc;
    __syncthreads();
    for (int d = 1; d < 256; d <<= 1) {
        int v = (t >= d) ? sh[t - d] : 0;
        __syncthreads();
        sh[t] += v;
        __syncthreads();
    }
    int excl = sh[t] - myc;
    int outbase = estart + nbase;            // earlier bins' self-loops = nbase
    int rp = outbase + excl;
    if (t < nin) {
        rowptr[nbase + t] = rp;
        cnt[nbase + t] = myc;
        esrc[rp] = nbase + t;                // self-loop in slot 0
    }
    lcur[t] = rp + (t < nin ? 1 : 0);
    __syncthreads();
    for (int e = estart + t; e < eend; e += 256) {
        int v = binned[e];
        int pos = atomicAdd(&lcur[(v >> 16) & 255], 1);
        esrc[pos] = v & 0xFFFF;
    }
}

// ---------------- attention layer 1 (wave per dst node) -----------------------
__global__ __launch_bounds__(256) void k_att1(
    const unsigned short* __restrict__ xp1b, const float* __restrict__ al1s,
    const float* __restrict__ al1d, const float* __restrict__ b1,
    const int* __restrict__ rowptr, const int* __restrict__ cnt,
    const int* __restrict__ esrc, unsigned short* __restrict__ h1b) {
    __shared__ int s_src[4][64];
    __shared__ float s_alpha[4][64 * 8];
    int wv = threadIdx.x >> 6;
    int lane = threadIdx.x & 63;
    int n = blockIdx.x * 4 + wv;          // grid exactly covers 50000 = 12500*4
    int start = rowptr[n];
    int deg = cnt[n];
    int dcap = deg < 64 ? deg : 64;
    for (int j = lane; j < dcap; j += 64) s_src[wv][j] = esrc[start + j];
    int h = lane & 7, eg = lane >> 3;
    float ald = al1d[n * NH + h];
    float m = -1e30f, den = 0.f;
    for (int j = eg; j < dcap; j += 8) {
        int s = s_src[wv][j];
        float v = al1s[s * NH + h] + ald;
        v = v > 0.f ? v : NEG * v;
        s_alpha[wv][j * 8 + h] = v;
        if (v > m) { den = den * __expf(m - v) + 1.f; m = v; }
        else den += __expf(v - m);
    }
    for (int j = 64 + eg; j < deg; j += 8) {      // rare tail
        int s = esrc[start + j];
        float v = al1s[s * NH + h] + ald;
        v = v > 0.f ? v : NEG * v;
        if (v > m) { den = den * __expf(m - v) + 1.f; m = v; }
        else den += __expf(v - m);
    }
    for (int msk = 8; msk < 64; msk <<= 1) {
        float mo = __shfl_xor(m, msk), dn = __shfl_xor(den, msk);
        float nm = fmaxf(m, mo);
        den = den * __expf(m - nm) + dn * __expf(mo - nm);
        m = nm;
    }
    float rden1 = 1.f / den;
    for (int j = eg; j < dcap; j += 8) {
        float v = s_alpha[wv][j * 8 + h];
        s_alpha[wv][j * 8 + h] = __expf(v - m) * rden1;
    }
    // pass 2: full-wave per edge; lane owns 4 channels; 8 edges in flight
    int hh = lane >> 3;
    int cb = lane << 2;
    float m2 = __shfl(m, hh);
    float rd2 = __shfl(rden1, hh);
    float ald2 = al1d[n * NH + hh];
    float a0 = 0.f, a1 = 0.f, a2 = 0.f, a3 = 0.f;
    for (int j0 = 0; j0 < dcap; j0 += 8) {
        const unsigned short* p[8];
        float aw[8];
#pragma unroll
        for (int k = 0; k < 8; ++k) {
            int e = j0 + k;
            bool act = e < dcap;
            int ee = act ? e : 0;
            int s = s_src[wv][ee];
            aw[k] = act ? s_alpha[wv][ee * 8 + hh] : 0.f;
            p[k] = xp1b + (size_t)s * D1 + cb;
        }
#pragma unroll
        for (int k = 0; k < 8; ++k) {
            u16x4 xv = *(const u16x4*)p[k];
            a0 = fmaf(aw[k], bf2f(xv[0]), a0);
            a1 = fmaf(aw[k], bf2f(xv[1]), a1);
            a2 = fmaf(aw[k], bf2f(xv[2]), a2);
            a3 = fmaf(aw[k], bf2f(xv[3]), a3);
        }
    }
    for (int j = 64; j < deg; ++j) {      // rare tail
        int s = esrc[start + j];
        float v = al1s[s * NH + hh] + ald2;
        v = v > 0.f ? v : NEG * v;
        float al = __expf(v - m2) * rd2;
        u16x4 xv = *(const u16x4*)(xp1b + (size_t)s * D1 + cb);
        a0 = fmaf(al, bf2f(xv[0]), a0);
        a1 = fmaf(al, bf2f(xv[1]), a1);
        a2 = fmaf(al, bf2f(xv[2]), a2);
        a3 = fmaf(al, bf2f(xv[3]), a3);
    }
    float4 bb = *(const float4*)(b1 + cb);
    a0 += bb.x; a1 += bb.y; a2 += bb.z; a3 += bb.w;
    a0 = a0 > 0.f ? a0 : expm1f(a0);
    a1 = a1 > 0.f ? a1 : expm1f(a1);
    a2 = a2 > 0.f ? a2 : expm1f(a2);
    a3 = a3 > 0.f ? a3 : expm1f(a3);
    u16x4 pk = { f2bf(a0), f2bf(a1), f2bf(a2), f2bf(a3) };
    *(u16x4*)(h1b + (size_t)n * D1 + cb) = pk;
}

// ---------------- GEMM2 (bf16 h1 in, broadcast W2) + al2 epilogue -------------
__global__ __launch_bounds__(256) void k_gemm2(
    const unsigned short* __restrict__ h1b, const float* __restrict__ W2,
    const float* __restrict__ a2s, const float* __restrict__ a2d,
    float* __restrict__ xp2, float* __restrict__ al2s, float* __restrict__ al2d) {
    __shared__ float w2s[D1 * NCLS];
    for (int i = threadIdx.x; i < D1 * NCLS; i += 256) w2s[i] = W2[i];
    __syncthreads();
    int n = blockIdx.x * 256 + threadIdx.x;
    if (n >= N_NODES) return;
    float4 acc[4];
#pragma unroll
    for (int q = 0; q < 4; ++q) acc[q] = make_float4(0.f, 0.f, 0.f, 0.f);
    const unsigned short* hr = h1b + (size_t)n * D1;
    for (int k0 = 0; k0 < D1; k0 += 8) {
        u16x8 hv = *(const u16x8*)(hr + k0);
#pragma unroll
        for (int j = 0; j < 8; ++j) {
            float hx = bf2f(hv[j]);
#pragma unroll
            for (int q = 0; q < 4; ++q) {
                float4 w = *(const float4*)(&w2s[(k0 + j) * NCLS + q * 4]);
                acc[q].x = fmaf(hx, w.x, acc[q].x);
                acc[q].y = fmaf(hx, w.y, acc[q].y);
                acc[q].z = fmaf(hx, w.z, acc[q].z);
                acc[q].w = fmaf(hx, w.w, acc[q].w);
            }
        }
    }
    float ss = 0.f, dd = 0.f;
#pragma unroll
    for (int q = 0; q < 4; ++q) {
        *(float4*)(xp2 + (size_t)n * NCLS + q * 4) = acc[q];
        float4 s4 = *(const float4*)(a2s + q * 4);
        float4 d4 = *(const float4*)(a2d + q * 4);
        ss += acc[q].x * s4.x + acc[q].y * s4.y + acc[q].z * s4.z + acc[q].w * s4.w;
        dd += acc[q].x * d4.x + acc[q].y * d4.y + acc[q].z * d4.z + acc[q].w * d4.w;
    }
    al2s[n] = ss;
    al2d[n] = dd;
}

// ---------------- attention layer 2 (wave per dst node) -----------------------
__global__ __launch_bounds__(256) void k_att2(
    const float* __restrict__ xp2, const float* __restrict__ al2s,
    const float* __restrict__ al2d, const float* __restrict__ b2,
    const int* __restrict__ rowptr, const int* __restrict__ cnt,
    const int* __restrict__ esrc, float* __restrict__ out2) {
    __shared__ int s_src[4][64];
    __shared__ float s_a[4][64];
    int wave = threadIdx.x >> 6;
    int lane = threadIdx.x & 63;
    int n = blockIdx.x * 4 + wave;
    int start = rowptr[n];
    int deg = cnt[n];
    int dcap = deg < 64 ? deg : 64;
    float ald = al2d[n];
    float m = -1e30f, den = 0.f;
    for (int j = lane; j < dcap; j += 64) {
        int s = esrc[start + j];
        s_src[wave][j] = s;
        float v = al2s[s] + ald;
        v = v > 0.f ? v : NEG * v;
        s_a[wave][j] = v;
        if (v > m) { den = den * __expf(m - v) + 1.f; m = v; }
        else den += __expf(v - m);
    }
    for (int j = 64 + lane; j < deg; j += 64) {   // rare tail
        float v = al2s[esrc[start + j]] + ald;
        v = v > 0.f ? v : NEG * v;
        if (v > m) { den = den * __expf(m - v) + 1.f; m = v; }
        else den += __expf(v - m);
    }
    for (int msk = 1; msk < 64; msk <<= 1) {
        float mo = __shfl_xor(m, msk), dn = __shfl_xor(den, msk);
        float nm = fmaxf(m, mo);
        den = den * __expf(m - nm) + dn * __expf(mo - nm);
        m = nm;
    }
    float rden = 1.f / den;
    for (int j = lane; j < dcap; j += 64)
        s_a[wave][j] = __expf(s_a[wave][j] - m) * rden;
    int c = lane & 15;
    int eg = lane >> 4;                   // 4 edges x 16 channels
    float acc = 0.f;
    for (int j = eg; j < dcap; j += 4)
        acc += s_a[wave][j] * xp2[(size_t)s_src[wave][j] * NCLS + c];
    for (int j = 64 + eg; j < deg; j += 4) {      // rare tail
        int s = esrc[start + j];
        float v = al2s[s] + ald;
        v = v > 0.f ? v : NEG * v;
        acc += __expf(v - m) * rden * xp2[(size_t)s * NCLS + c];
    }
    acc += __shfl_xor(acc, 16);
    acc += __shfl_xor(acc, 32);
    if (lane < 16) out2[(size_t)n * NCLS + lane] = acc + b2[lane];
}

// ---------------- pooling (LDS pre-aggregation, sorted batch) -----------------
__global__ __launch_bounds__(256) void k_pool(
    const float* __restrict__ out2, const int* __restrict__ batch,
    float* __restrict__ poolS, float* __restrict__ poolC) {
    __shared__ float sacc[NGRP * NCLS];
    __shared__ float scnt[NGRP];
    for (int i = threadIdx.x; i < NGRP * NCLS; i += 256) sacc[i] = 0.f;
    if (threadIdx.x < NGRP) scnt[threadIdx.x] = 0.f;
    __syncthreads();
    int n = blockIdx.x * 256 + threadIdx.x;
    if (n < N_NODES) {
        int g = batch[n];
        atomicAdd(&scnt[g], 1.f);
#pragma unroll
        for (int cc = 0; cc < NCLS; ++cc)
            atomicAdd(&sacc[g * NCLS + cc], out2[(size_t)n * NCLS + cc]);
    }
    __syncthreads();
    for (int i = threadIdx.x; i < NGRP * NCLS; i += 256)
        if (sacc[i] != 0.f) atomicAdd(&poolS[i], sacc[i]);
    if (threadIdx.x < NGRP && scnt[threadIdx.x] != 0.f)
        atomicAdd(&poolC[threadIdx.x], scnt[threadIdx.x]);
}

__global__ void k_final(const float* __restrict__ poolS,
                        const float* __restrict__ poolC, float* __restrict__ out) {
    int g = threadIdx.x;
    if (g >= NGRP) return;
    float inv = 1.f / fmaxf(poolC[g], 1.f);
    float v[NCLS];
    float m = -1e30f;
#pragma unroll
    for (int c = 0; c < NCLS; ++c) {
        v[c] = poolS[g * NCLS + c] * inv;
        m = fmaxf(m, v[c]);
    }
    float s = 0.f;
#pragma unroll
    for (int c = 0; c < NCLS; ++c) s += expf(v[c] - m);
    float lse = m + logf(s);
#pragma unroll
    for (int c = 0; c < NCLS; ++c) out[g * NCLS + c] = v[c] - lse;
}

extern "C" void kernel_launch(void* const* d_in, const int* in_sizes, int n_in,
                              void* d_out, int out_size, void* d_ws, size_t ws_size,
                              hipStream_t stream) {
    const float* x    = (const float*)d_in[0];
    const int*   ei   = (const int*)d_in[1];
    const int*   batch = (const int*)d_in[2];
    const float* W1   = (const float*)d_in[3];
    const float* a1s  = (const float*)d_in[4];
    const float* a1d  = (const float*)d_in[5];
    const float* b1   = (const float*)d_in[6];
    const float* W2   = (const float*)d_in[7];
    const float* a2s  = (const float*)d_in[8];
    const float* a2d  = (const float*)d_in[9];
    const float* b2   = (const float*)d_in[10];
    float* out = (float*)d_out;

    float* f = (float*)d_ws;
    float* al1s_ = f;  f += (size_t)N_NODES * NH;
    float* al1d_ = f;  f += (size_t)N_NODES * NH;
    float* xp2   = f;  f += (size_t)N_NODES * NCLS;
    float* al2s_ = f;  f += N_NODES;
    float* al2d_ = f;  f += N_NODES;
    float* out2  = f;  f += (size_t)N_NODES * NCLS;
    float* poolS = f;  f += NGRP * NCLS;
    float* poolC = f;  f += NGRP;
    unsigned short* xp1b = (unsigned short*)f;
    unsigned short* h1b  = xp1b + (size_t)N_NODES * D1;
    unsigned short* w1p  = h1b + (size_t)N_NODES * D1;
    int* binmat = (int*)(w1p + FDIM * D1);
    int* binned = binmat + NBIN * NCHUNK;
    int* rowptr = binned + N_EDGES;
    int* cnt    = rowptr + N_NODES;
    int* esrc   = cnt + N_NODES;

    k_init<<<NB_N, 256, 0, stream>>>(W1, w1p, poolS, poolC);
    k_gemm1m<<<G1_BLOCKS, 256, 0, stream>>>(x, w1p, a1s, a1d, xp1b, al1s_, al1d_);
    k_binhist<<<NCHUNK, 256, 0, stream>>>(ei, binmat);
    k_binscan<<<1, 1024, 0, stream>>>(binmat);
    k_binscatter<<<NCHUNK, 256, 0, stream>>>(ei, binmat, binned);
    k_bincsr<<<NBIN, 256, 0, stream>>>(binmat, binned, rowptr, cnt, esrc);
    k_att1<<<N_NODES / 4, 256, 0, stream>>>(xp1b, al1s_, al1d_, b1, rowptr, cnt, esrc, h1b);
    k_gemm2<<<NB_N, 256, 0, stream>>>(h1b, W2, a2s, a2d, xp2, al2s_, al2d_);
    k_att2<<<N_NODES / 4, 256, 0, stream>>>(xp2, al2s_, al2d_, b2, rowptr, cnt, esrc, out2);
    k_pool<<<NB_N, 256, 0, stream>>>(out2, batch, poolS, poolC);
    k_final<<<1, 64, 0, stream>>>(poolS, poolC, out);
}

// Round 9
// 238.553 us; speedup vs baseline: 1.4824x; 1.0529x over previous
//
#include <hip/hip_runtime.h>
#include <math.h>

#define N_NODES 50000
#define N_EDGES 800000
#define FDIM 128
#define NH 8
#define NC 32
#define D1 256      // NH*NC
#define NCLS 16
#define NGRP 64
#define NEG 0.2f
#define E_TOT (N_EDGES + N_NODES)
#define NB_N 196        // (N_NODES+255)/256
#define G1_BLOCKS 782   // (N_NODES+63)/64
#define E_CHUNK 4096
#define NCHUNK 196      // ceil(800000/4096)
#define NBIN 196        // ceil(50000/256)

typedef __attribute__((ext_vector_type(8))) unsigned short u16x8;
typedef __attribute__((ext_vector_type(4))) unsigned short u16x4;
typedef __attribute__((ext_vector_type(8))) short short8;
typedef __attribute__((ext_vector_type(4))) float f32x4;

static __device__ __forceinline__ float bf2f(unsigned short u) {
    return __uint_as_float(((unsigned int)u) << 16);
}
static __device__ __forceinline__ unsigned short f2bf(float f) {
    unsigned int b = __float_as_uint(f);
    return (unsigned short)((b + 0x7FFFu + ((b >> 16) & 1u)) >> 16);
}

// ---- init (pool zero + W1 pack) FUSED with per-chunk bin histogram -----------
__global__ __launch_bounds__(256) void k_init(
    const float* __restrict__ W1, unsigned short* __restrict__ w1p,
    float* __restrict__ poolS, float* __restrict__ poolC,
    const int* __restrict__ ei, int* __restrict__ binmat) {
    __shared__ int h[NBIN];
    int c = blockIdx.x;
    for (int b = threadIdx.x; b < NBIN; b += 256) h[b] = 0;
    __syncthreads();
    int e0 = c * E_CHUNK;
    int e1 = e0 + E_CHUNK; if (e1 > N_EDGES) e1 = N_EDGES;
    for (int e = e0 + threadIdx.x; e < e1; e += 256)
        atomicAdd(&h[ei[N_EDGES + e] >> 8], 1);
    // independent init work while histogram atomics settle
    int i = blockIdx.x * 256 + threadIdx.x;
    if (i < NGRP * NCLS) poolS[i] = 0.f;
    if (i < NGRP) poolC[i] = 0.f;
    if (i < FDIM * D1) {
        int ks = i >> 13;
        int r = i & 8191;
        int nt2 = r >> 9;
        int r2 = r & 511;
        int lane = r2 >> 3, e = r2 & 7;
        int k = ks * 32 + (lane >> 4) * 8 + e;
        int col = nt2 * 16 + (lane & 15);
        w1p[i] = f2bf(W1[k * D1 + col]);
    }
    __syncthreads();
    for (int b = threadIdx.x; b < NBIN; b += 256) binmat[b * NCHUNK + c] = h[b];
}

// ------ GEMM1 via MFMA bf16 + fused al1; block G1_BLOCKS does the bin scan ----
__global__ __launch_bounds__(256) void k_gemm1m(
    const float* __restrict__ x, const unsigned short* __restrict__ w1p,
    const float* __restrict__ a1s, const float* __restrict__ a1d,
    unsigned short* __restrict__ xp1b, float* __restrict__ al1s,
    float* __restrict__ al1d, int* __restrict__ binmat) {
    if (blockIdx.x == G1_BLOCKS) {
        // exclusive scan of binmat (bin-major), overlapped with GEMM blocks
        __shared__ int sh[256];
        const int TOT = NBIN * NCHUNK;          // 38416
        const int PER = (TOT + 255) / 256;      // 151
        int t = threadIdx.x;
        int i0 = t * PER;
        int i1 = i0 + PER; if (i1 > TOT) i1 = TOT;
        int sum = 0;
        for (int i = i0; i < i1; ++i) sum += binmat[i];
        sh[t] = sum;
        __syncthreads();
        for (int d = 1; d < 256; d <<= 1) {
            int v = (t >= d) ? sh[t - d] : 0;
            __syncthreads();
            sh[t] += v;
            __syncthreads();
        }
        int run = (t == 0) ? 0 : sh[t - 1];
        for (int i = i0; i < i1; ++i) {
            int v = binmat[i];
            binmat[i] = run;
            run += v;
        }
        return;
    }
    const int l = threadIdx.x & 63;
    const int wid = threadIdx.x >> 6;
    const int wr = wid >> 1, wc = wid & 1;
    const int l15 = l & 15, l4 = l >> 4;
    const int base = blockIdx.x * 64;
    const int r0 = base + wr * 32;

    f32x4 acc[2][8] = {};
#pragma unroll
    for (int ks = 0; ks < 4; ++ks) {
        const int kk = ks * 32 + l4 * 8;
        short8 af[2];
#pragma unroll
        for (int rt = 0; rt < 2; ++rt) {
            int row = r0 + rt * 16 + l15;
            float4 v0 = make_float4(0.f, 0.f, 0.f, 0.f), v1 = v0;
            if (row < N_NODES) {
                const float* xr = x + (size_t)row * FDIM + kk;
                v0 = *(const float4*)xr;
                v1 = *(const float4*)(xr + 4);
            }
            short8 a;
            a[0] = (short)f2bf(v0.x); a[1] = (short)f2bf(v0.y);
            a[2] = (short)f2bf(v0.z); a[3] = (short)f2bf(v0.w);
            a[4] = (short)f2bf(v1.x); a[5] = (short)f2bf(v1.y);
            a[6] = (short)f2bf(v1.z); a[7] = (short)f2bf(v1.w);
            af[rt] = a;
        }
#pragma unroll
        for (int nt = 0; nt < 8; ++nt) {
            int nt2 = wc * 8 + nt;
            short8 bf_ = *(const short8*)&w1p[(size_t)((ks * 16 + nt2) * 64 + l) * 8];
            acc[0][nt] = __builtin_amdgcn_mfma_f32_16x16x32_bf16(af[0], bf_, acc[0][nt], 0, 0, 0);
            acc[1][nt] = __builtin_amdgcn_mfma_f32_16x16x32_bf16(af[1], bf_, acc[1][nt], 0, 0, 0);
        }
    }
#pragma unroll
    for (int rt = 0; rt < 2; ++rt) {
        int rbase = r0 + rt * 16 + l4 * 4;
#pragma unroll
        for (int nt = 0; nt < 8; ++nt) {
            int col = wc * 128 + nt * 16 + l15;
            f32x4 c = acc[rt][nt];
#pragma unroll
            for (int r = 0; r < 4; ++r) {
                int row = rbase + r;
                if (row < N_NODES) xp1b[(size_t)row * D1 + col] = f2bf(c[r]);
            }
        }
    }
#pragma unroll
    for (int hl = 0; hl < 4; ++hl) {
        int hg = wc * 4 + hl;
        float as0 = a1s[hg * NC + l15], as1 = a1s[hg * NC + 16 + l15];
        float ad0 = a1d[hg * NC + l15], ad1 = a1d[hg * NC + 16 + l15];
#pragma unroll
        for (int rt = 0; rt < 2; ++rt) {
            f32x4 c0 = acc[rt][2 * hl], c1 = acc[rt][2 * hl + 1];
#pragma unroll
            for (int r = 0; r < 4; ++r) {
                float ss = c0[r] * as0 + c1[r] * as1;
                float dd = c0[r] * ad0 + c1[r] * ad1;
#pragma unroll
                for (int msk = 1; msk < 16; msk <<= 1) {
                    ss += __shfl_xor(ss, msk);
                    dd += __shfl_xor(dd, msk);
                }
                int row = r0 + rt * 16 + l4 * 4 + r;
                if (l15 == 0 && row < N_NODES) {
                    al1s[row * NH + hg] = ss;
                    al1d[row * NH + hg] = dd;
                }
            }
        }
    }
}

// ---- scatter edges to bin-grouped array via LDS cursors ----------------------
__global__ __launch_bounds__(256) void k_binscatter(const int* __restrict__ ei,
                                                    const int* __restrict__ offs,
                                                    int* __restrict__ binned) {
    __shared__ int cur[NBIN];
    int c = blockIdx.x;
    for (int b = threadIdx.x; b < NBIN; b += 256) cur[b] = offs[b * NCHUNK + c];
    __syncthreads();
    int e0 = c * E_CHUNK;
    int e1 = e0 + E_CHUNK; if (e1 > N_EDGES) e1 = N_EDGES;
    for (int e = e0 + threadIdx.x; e < e1; e += 256) {
        int s = ei[e], d = ei[N_EDGES + e];
        int pos = atomicAdd(&cur[d >> 8], 1);
        binned[pos] = s | ((d & 255) << 16);   // src < 65536
    }
}

// ---- per-bin CSR finalize (rowptr/cnt/esrc incl. self-loops) -----------------
__global__ __launch_bounds__(256) void k_bincsr(const int* __restrict__ offs,
                                                const int* __restrict__ binned,
                                                int* __restrict__ rowptr,
                                                int* __restrict__ cnt,
                                                int* __restrict__ esrc) {
    __shared__ int lcnt[256];
    __shared__ int sh[256];
    __shared__ int lcur[256];
    int b = blockIdx.x;
    int t = threadIdx.x;
    int estart = offs[b * NCHUNK];
    int eend = (b == NBIN - 1) ? N_EDGES : offs[(b + 1) * NCHUNK];
    int nbase = b * 256;
    int nin = N_NODES - nbase; if (nin > 256) nin = 256;
    lcnt[t] = 0;
    __syncthreads();
    for (int e = estart + t; e < eend; e += 256)
        atomicAdd(&lcnt[(binned[e] >> 16) & 255], 1);
    __syncthreads();
    int myc = lcnt[t] + (t < nin ? 1 : 0);   // + self loop
    sh[t] = myc;
    __syncthreads();
    for (int d = 1; d < 256; d <<= 1) {
        int v = (t >= d) ? sh[t - d] : 0;
        __syncthreads();
        sh[t] += v;
        __syncthreads();
    }
    int excl = sh[t] - myc;
    int outbase = estart + nbase;            // earlier bins' self-loops = nbase
    int rp = outbase + excl;
    if (t < nin) {
        rowptr[nbase + t] = rp;
        cnt[nbase + t] = myc;
        esrc[rp] = nbase + t;                // self-loop in slot 0
    }
    lcur[t] = rp + (t < nin ? 1 : 0);
    __syncthreads();
    for (int e = estart + t; e < eend; e += 256) {
        int v = binned[e];
        int pos = atomicAdd(&lcur[(v >> 16) & 255], 1);
        esrc[pos] = v & 0xFFFF;
    }
}

// ---------------- attention layer 1 (wave per dst node) -----------------------
__global__ __launch_bounds__(256) void k_att1(
    const unsigned short* __restrict__ xp1b, const float* __restrict__ al1s,
    const float* __restrict__ al1d, const float* __restrict__ b1,
    const int* __restrict__ rowptr, const int* __restrict__ cnt,
    const int* __restrict__ esrc, unsigned short* __restrict__ h1b) {
    __shared__ int s_src[4][64];
    __shared__ float s_alpha[4][64 * 8];
    int wv = threadIdx.x >> 6;
    int lane = threadIdx.x & 63;
    int n = blockIdx.x * 4 + wv;          // grid exactly covers 50000 = 12500*4
    int start = rowptr[n];
    int deg = cnt[n];
    int dcap = deg < 64 ? deg : 64;
    for (int j = lane; j < dcap; j += 64) s_src[wv][j] = esrc[start + j];
    int h = lane & 7, eg = lane >> 3;
    float ald = al1d[n * NH + h];
    float m = -1e30f, den = 0.f;
    for (int j = eg; j < dcap; j += 8) {
        int s = s_src[wv][j];
        float v = al1s[s * NH + h] + ald;
        v = v > 0.f ? v : NEG * v;
        s_alpha[wv][j * 8 + h] = v;
        if (v > m) { den = den * __expf(m - v) + 1.f; m = v; }
        else den += __expf(v - m);
    }
    for (int j = 64 + eg; j < deg; j += 8) {      // rare tail
        int s = esrc[start + j];
        float v = al1s[s * NH + h] + ald;
        v = v > 0.f ? v : NEG * v;
        if (v > m) { den = den * __expf(m - v) + 1.f; m = v; }
        else den += __expf(v - m);
    }
    for (int msk = 8; msk < 64; msk <<= 1) {
        float mo = __shfl_xor(m, msk), dn = __shfl_xor(den, msk);
        float nm = fmaxf(m, mo);
        den = den * __expf(m - nm) + dn * __expf(mo - nm);
        m = nm;
    }
    float rden1 = 1.f / den;
    for (int j = eg; j < dcap; j += 8) {
        float v = s_alpha[wv][j * 8 + h];
        s_alpha[wv][j * 8 + h] = __expf(v - m) * rden1;
    }
    // pass 2: full-wave per edge; lane owns 4 channels; 8 edges in flight
    int hh = lane >> 3;
    int cb = lane << 2;
    float m2 = __shfl(m, hh);
    float rd2 = __shfl(rden1, hh);
    float ald2 = al1d[n * NH + hh];
    float a0 = 0.f, a1 = 0.f, a2 = 0.f, a3 = 0.f;
    for (int j0 = 0; j0 < dcap; j0 += 8) {
        const unsigned short* p[8];
        float aw[8];
#pragma unroll
        for (int k = 0; k < 8; ++k) {
            int e = j0 + k;
            bool act = e < dcap;
            int ee = act ? e : 0;
            int s = s_src[wv][ee];
            aw[k] = act ? s_alpha[wv][ee * 8 + hh] : 0.f;
            p[k] = xp1b + (size_t)s * D1 + cb;
        }
#pragma unroll
        for (int k = 0; k < 8; ++k) {
            u16x4 xv = *(const u16x4*)p[k];
            a0 = fmaf(aw[k], bf2f(xv[0]), a0);
            a1 = fmaf(aw[k], bf2f(xv[1]), a1);
            a2 = fmaf(aw[k], bf2f(xv[2]), a2);
            a3 = fmaf(aw[k], bf2f(xv[3]), a3);
        }
    }
    for (int j = 64; j < deg; ++j) {      // rare tail
        int s = esrc[start + j];
        float v = al1s[s * NH + hh] + ald2;
        v = v > 0.f ? v : NEG * v;
        float al = __expf(v - m2) * rd2;
        u16x4 xv = *(const u16x4*)(xp1b + (size_t)s * D1 + cb);
        a0 = fmaf(al, bf2f(xv[0]), a0);
        a1 = fmaf(al, bf2f(xv[1]), a1);
        a2 = fmaf(al, bf2f(xv[2]), a2);
        a3 = fmaf(al, bf2f(xv[3]), a3);
    }
    float4 bb = *(const float4*)(b1 + cb);
    a0 += bb.x; a1 += bb.y; a2 += bb.z; a3 += bb.w;
    a0 = a0 > 0.f ? a0 : expm1f(a0);
    a1 = a1 > 0.f ? a1 : expm1f(a1);
    a2 = a2 > 0.f ? a2 : expm1f(a2);
    a3 = a3 > 0.f ? a3 : expm1f(a3);
    u16x4 pk = { f2bf(a0), f2bf(a1), f2bf(a2), f2bf(a3) };
    *(u16x4*)(h1b + (size_t)n * D1 + cb) = pk;
}

// ---------------- GEMM2 (bf16 h1 in, broadcast W2) + al2 epilogue -------------
__global__ __launch_bounds__(256) void k_gemm2(
    const unsigned short* __restrict__ h1b, const float* __restrict__ W2,
    const float* __restrict__ a2s, const float* __restrict__ a2d,
    float* __restrict__ xp2, float* __restrict__ al2s, float* __restrict__ al2d) {
    __shared__ float w2s[D1 * NCLS];
    for (int i = threadIdx.x; i < D1 * NCLS; i += 256) w2s[i] = W2[i];
    __syncthreads();
    int n = blockIdx.x * 256 + threadIdx.x;
    if (n >= N_NODES) return;
    float4 acc[4];
#pragma unroll
    for (int q = 0; q < 4; ++q) acc[q] = make_float4(0.f, 0.f, 0.f, 0.f);
    const unsigned short* hr = h1b + (size_t)n * D1;
    for (int k0 = 0; k0 < D1; k0 += 8) {
        u16x8 hv = *(const u16x8*)(hr + k0);
#pragma unroll
        for (int j = 0; j < 8; ++j) {
            float hx = bf2f(hv[j]);
#pragma unroll
            for (int q = 0; q < 4; ++q) {
                float4 w = *(const float4*)(&w2s[(k0 + j) * NCLS + q * 4]);
                acc[q].x = fmaf(hx, w.x, acc[q].x);
                acc[q].y = fmaf(hx, w.y, acc[q].y);
                acc[q].z = fmaf(hx, w.z, acc[q].z);
                acc[q].w = fmaf(hx, w.w, acc[q].w);
            }
        }
    }
    float ss = 0.f, dd = 0.f;
#pragma unroll
    for (int q = 0; q < 4; ++q) {
        *(float4*)(xp2 + (size_t)n * NCLS + q * 4) = acc[q];
        float4 s4 = *(const float4*)(a2s + q * 4);
        float4 d4 = *(const float4*)(a2d + q * 4);
        ss += acc[q].x * s4.x + acc[q].y * s4.y + acc[q].z * s4.z + acc[q].w * s4.w;
        dd += acc[q].x * d4.x + acc[q].y * d4.y + acc[q].z * d4.z + acc[q].w * d4.w;
    }
    al2s[n] = ss;
    al2d[n] = dd;
}

// ---------------- attention layer 2 (wave per dst node) -----------------------
__global__ __launch_bounds__(256) void k_att2(
    const float* __restrict__ xp2, const float* __restrict__ al2s,
    const float* __restrict__ al2d, const float* __restrict__ b2,
    const int* __restrict__ rowptr, const int* __restrict__ cnt,
    const int* __restrict__ esrc, float* __restrict__ out2) {
    __shared__ int s_src[4][64];
    __shared__ float s_a[4][64];
    int wave = threadIdx.x >> 6;
    int lane = threadIdx.x & 63;
    int n = blockIdx.x * 4 + wave;
    int start = rowptr[n];
    int deg = cnt[n];
    int dcap = deg < 64 ? deg : 64;
    float ald = al2d[n];
    float m = -1e30f, den = 0.f;
    for (int j = lane; j < dcap; j += 64) {
        int s = esrc[start + j];
        s_src[wave][j] = s;
        float v = al2s[s] + ald;
        v = v > 0.f ? v : NEG * v;
        s_a[wave][j] = v;
        if (v > m) { den = den * __expf(m - v) + 1.f; m = v; }
        else den += __expf(v - m);
    }
    for (int j = 64 + lane; j < deg; j += 64) {   // rare tail
        float v = al2s[esrc[start + j]] + ald;
        v = v > 0.f ? v : NEG * v;
        if (v > m) { den = den * __expf(m - v) + 1.f; m = v; }
        else den += __expf(v - m);
    }
    for (int msk = 1; msk < 64; msk <<= 1) {
        float mo = __shfl_xor(m, msk), dn = __shfl_xor(den, msk);
        float nm = fmaxf(m, mo);
        den = den * __expf(m - nm) + dn * __expf(mo - nm);
        m = nm;
    }
    float rden = 1.f / den;
    for (int j = lane; j < dcap; j += 64)
        s_a[wave][j] = __expf(s_a[wave][j] - m) * rden;
    int c = lane & 15;
    int eg = lane >> 4;                   // 4 edges x 16 channels, 2-deep unroll
    float acc = 0.f;
    for (int j0 = 0; j0 < dcap; j0 += 8) {
        const float* p[2];
        float aw[2];
#pragma unroll
        for (int k = 0; k < 2; ++k) {
            int e = j0 + eg + 4 * k;
            bool act = e < dcap;
            int ee = act ? e : 0;
            aw[k] = act ? s_a[wave][ee] : 0.f;
            p[k] = xp2 + (size_t)s_src[wave][ee] * NCLS + c;
        }
        acc = fmaf(aw[0], p[0][0], acc);
        acc = fmaf(aw[1], p[1][0], acc);
    }
    for (int j = 64 + eg; j < deg; j += 4) {      // rare tail
        int s = esrc[start + j];
        float v = al2s[s] + ald;
        v = v > 0.f ? v : NEG * v;
        acc += __expf(v - m) * rden * xp2[(size_t)s * NCLS + c];
    }
    acc += __shfl_xor(acc, 16);
    acc += __shfl_xor(acc, 32);
    if (lane < 16) out2[(size_t)n * NCLS + lane] = acc + b2[lane];
}

// ---------------- pooling (LDS pre-aggregation, sorted batch) -----------------
__global__ __launch_bounds__(256) void k_pool(
    const float* __restrict__ out2, const int* __restrict__ batch,
    float* __restrict__ poolS, float* __restrict__ poolC) {
    __shared__ float sacc[NGRP * NCLS];
    __shared__ float scnt[NGRP];
    for (int i = threadIdx.x; i < NGRP * NCLS; i += 256) sacc[i] = 0.f;
    if (threadIdx.x < NGRP) scnt[threadIdx.x] = 0.f;
    __syncthreads();
    int n = blockIdx.x * 256 + threadIdx.x;
    if (n < N_NODES) {
        int g = batch[n];
        atomicAdd(&scnt[g], 1.f);
#pragma unroll
        for (int q = 0; q < 4; ++q) {
            float4 v = *(const float4*)(out2 + (size_t)n * NCLS + q * 4);
            atomicAdd(&sacc[g * NCLS + q * 4 + 0], v.x);
            atomicAdd(&sacc[g * NCLS + q * 4 + 1], v.y);
            atomicAdd(&sacc[g * NCLS + q * 4 + 2], v.z);
            atomicAdd(&sacc[g * NCLS + q * 4 + 3], v.w);
        }
    }
    __syncthreads();
    for (int i = threadIdx.x; i < NGRP * NCLS; i += 256)
        if (sacc[i] != 0.f) atomicAdd(&poolS[i], sacc[i]);
    if (threadIdx.x < NGRP && scnt[threadIdx.x] != 0.f)
        atomicAdd(&poolC[threadIdx.x], scnt[threadIdx.x]);
}

__global__ void k_final(const float* __restrict__ poolS,
                        const float* __restrict__ poolC, float* __restrict__ out) {
    int g = threadIdx.x;
    if (g >= NGRP) return;
    float inv = 1.f / fmaxf(poolC[g], 1.f);
    float v[NCLS];
    float m = -1e30f;
#pragma unroll
    for (int c = 0; c < NCLS; ++c) {
        v[c] = poolS[g * NCLS + c] * inv;
        m = fmaxf(m, v[c]);
    }
    float s = 0.f;
#pragma unroll
    for (int c = 0; c < NCLS; ++c) s += expf(v[c] - m);
    float lse = m + logf(s);
#pragma unroll
    for (int c = 0; c < NCLS; ++c) out[g * NCLS + c] = v[c] - lse;
}

extern "C" void kernel_launch(void* const* d_in, const int* in_sizes, int n_in,
                              void* d_out, int out_size, void* d_ws, size_t ws_size,
                              hipStream_t stream) {
    const float* x    = (const float*)d_in[0];
    const int*   ei   = (const int*)d_in[1];
    const int*   batch = (const int*)d_in[2];
    const float* W1   = (const float*)d_in[3];
    const float* a1s  = (const float*)d_in[4];
    const float* a1d  = (const float*)d_in[5];
    const float* b1   = (const float*)d_in[6];
    const float* W2   = (const float*)d_in[7];
    const float* a2s  = (const float*)d_in[8];
    const float* a2d  = (const float*)d_in[9];
    const float* b2   = (const float*)d_in[10];
    float* out = (float*)d_out;

    float* f = (float*)d_ws;
    float* al1s_ = f;  f += (size_t)N_NODES * NH;
    float* al1d_ = f;  f += (size_t)N_NODES * NH;
    float* xp2   = f;  f += (size_t)N_NODES * NCLS;
    float* al2s_ = f;  f += N_NODES;
    float* al2d_ = f;  f += N_NODES;
    float* out2  = f;  f += (size_t)N_NODES * NCLS;
    float* poolS = f;  f += NGRP * NCLS;
    float* poolC = f;  f += NGRP;
    unsigned short* xp1b = (unsigned short*)f;
    unsigned short* h1b  = xp1b + (size_t)N_NODES * D1;
    unsigned short* w1p  = h1b + (size_t)N_NODES * D1;
    int* binmat = (int*)(w1p + FDIM * D1);
    int* binned = binmat + NBIN * NCHUNK;
    int* rowptr = binned + N_EDGES;
    int* cnt    = rowptr + N_NODES;
    int* esrc   = cnt + N_NODES;

    k_init<<<NB_N, 256, 0, stream>>>(W1, w1p, poolS, poolC, ei, binmat);
    k_gemm1m<<<G1_BLOCKS + 1, 256, 0, stream>>>(x, w1p, a1s, a1d, xp1b, al1s_, al1d_, binmat);
    k_binscatter<<<NCHUNK, 256, 0, stream>>>(ei, binmat, binned);
    k_bincsr<<<NBIN, 256, 0, stream>>>(binmat, binned, rowptr, cnt, esrc);
    k_att1<<<N_NODES / 4, 256, 0, stream>>>(xp1b, al1s_, al1d_, b1, rowptr, cnt, esrc, h1b);
    k_gemm2<<<NB_N, 256, 0, stream>>>(h1b, W2, a2s, a2d, xp2, al2s_, al2d_);
    k_att2<<<N_NODES / 4, 256, 0, stream>>>(xp2, al2s_, al2d_, b2, rowptr, cnt, esrc, out2);
    k_pool<<<NB_N, 256, 0, stream>>>(out2, batch, poolS, poolC);
    k_final<<<1, 64, 0, stream>>>(poolS, poolC, out);
}

// Round 10
// 193.431 us; speedup vs baseline: 1.8282x; 1.2333x over previous
//
#include <hip/hip_runtime.h>
#include <math.h>

#define N_NODES 50000
#define N_EDGES 800000
#define FDIM 128
#define NH 8
#define NC 32
#define D1 256      // NH*NC
#define NCLS 16
#define NGRP 64
#define NEG 0.2f
#define E_TOT (N_EDGES + N_NODES)
#define NB_N 196        // (N_NODES+255)/256
#define G1_BLOCKS 782   // (N_NODES+63)/64
#define E_CHUNK 4096
#define NCHUNK 196      // ceil(800000/4096)
#define NBIN 196        // ceil(50000/256)

typedef __attribute__((ext_vector_type(8))) unsigned short u16x8;
typedef __attribute__((ext_vector_type(4))) unsigned short u16x4;
typedef __attribute__((ext_vector_type(8))) short short8;
typedef __attribute__((ext_vector_type(4))) float f32x4;

static __device__ __forceinline__ float bf2f(unsigned short u) {
    return __uint_as_float(((unsigned int)u) << 16);
}
static __device__ __forceinline__ unsigned short f2bf(float f) {
    unsigned int b = __float_as_uint(f);
    return (unsigned short)((b + 0x7FFFu + ((b >> 16) & 1u)) >> 16);
}

// ---- init (pool zero + W1 pack) FUSED with per-chunk bin histogram -----------
__global__ __launch_bounds__(256) void k_init(
    const float* __restrict__ W1, unsigned short* __restrict__ w1p,
    float* __restrict__ poolS, float* __restrict__ poolC,
    const int* __restrict__ ei, int* __restrict__ binmat) {
    __shared__ int h[NBIN];
    int c = blockIdx.x;
    for (int b = threadIdx.x; b < NBIN; b += 256) h[b] = 0;
    __syncthreads();
    int e0 = c * E_CHUNK;
    int e1 = e0 + E_CHUNK; if (e1 > N_EDGES) e1 = N_EDGES;
    for (int e = e0 + threadIdx.x; e < e1; e += 256)
        atomicAdd(&h[ei[N_EDGES + e] >> 8], 1);
    // independent init work while histogram atomics settle
    int i = blockIdx.x * 256 + threadIdx.x;
    if (i < NGRP * NCLS) poolS[i] = 0.f;
    if (i < NGRP) poolC[i] = 0.f;
    if (i < FDIM * D1) {
        int ks = i >> 13;
        int r = i & 8191;
        int nt2 = r >> 9;
        int r2 = r & 511;
        int lane = r2 >> 3, e = r2 & 7;
        int k = ks * 32 + (lane >> 4) * 8 + e;
        int col = nt2 * 16 + (lane & 15);
        w1p[i] = f2bf(W1[k * D1 + col]);
    }
    __syncthreads();
    for (int b = threadIdx.x; b < NBIN; b += 256) binmat[b * NCHUNK + c] = h[b];
}

// ---- per-bin row scan: binmat[b][*] -> exclusive within-row prefix + total ---
__global__ __launch_bounds__(256) void k_binprescan(int* __restrict__ binmat,
                                                    int* __restrict__ binTot) {
    __shared__ int sh[256];
    int b = blockIdx.x, t = threadIdx.x;
    int v = (t < NCHUNK) ? binmat[b * NCHUNK + t] : 0;
    sh[t] = v;
    __syncthreads();
    for (int d = 1; d < 256; d <<= 1) {
        int tv = (t >= d) ? sh[t - d] : 0;
        __syncthreads();
        sh[t] += tv;
        __syncthreads();
    }
    if (t < NCHUNK) binmat[b * NCHUNK + t] = sh[t] - v;   // exclusive in-row
    if (t == 255) binTot[b] = sh[255];
}

// ---- scan of 196 bin totals -> binBase ---------------------------------------
__global__ __launch_bounds__(256) void k_basescan(const int* __restrict__ binTot,
                                                  int* __restrict__ binBase) {
    __shared__ int sh[256];
    int t = threadIdx.x;
    int v = (t < NBIN) ? binTot[t] : 0;
    sh[t] = v;
    __syncthreads();
    for (int d = 1; d < 256; d <<= 1) {
        int tv = (t >= d) ? sh[t - d] : 0;
        __syncthreads();
        sh[t] += tv;
        __syncthreads();
    }
    if (t < NBIN) binBase[t] = sh[t] - v;                 // exclusive
}

// ------ GEMM1 via MFMA bf16 (no LDS): xp1b = bf16(x)@bf16(W1), fused al1 ------
__global__ __launch_bounds__(256) void k_gemm1m(
    const float* __restrict__ x, const unsigned short* __restrict__ w1p,
    const float* __restrict__ a1s, const float* __restrict__ a1d,
    unsigned short* __restrict__ xp1b, float* __restrict__ al1s,
    float* __restrict__ al1d) {
    const int l = threadIdx.x & 63;
    const int wid = threadIdx.x >> 6;
    const int wr = wid >> 1, wc = wid & 1;
    const int l15 = l & 15, l4 = l >> 4;
    const int base = blockIdx.x * 64;
    const int r0 = base + wr * 32;

    f32x4 acc[2][8] = {};
#pragma unroll
    for (int ks = 0; ks < 4; ++ks) {
        const int kk = ks * 32 + l4 * 8;
        short8 af[2];
#pragma unroll
        for (int rt = 0; rt < 2; ++rt) {
            int row = r0 + rt * 16 + l15;
            float4 v0 = make_float4(0.f, 0.f, 0.f, 0.f), v1 = v0;
            if (row < N_NODES) {
                const float* xr = x + (size_t)row * FDIM + kk;
                v0 = *(const float4*)xr;
                v1 = *(const float4*)(xr + 4);
            }
            short8 a;
            a[0] = (short)f2bf(v0.x); a[1] = (short)f2bf(v0.y);
            a[2] = (short)f2bf(v0.z); a[3] = (short)f2bf(v0.w);
            a[4] = (short)f2bf(v1.x); a[5] = (short)f2bf(v1.y);
            a[6] = (short)f2bf(v1.z); a[7] = (short)f2bf(v1.w);
            af[rt] = a;
        }
#pragma unroll
        for (int nt = 0; nt < 8; ++nt) {
            int nt2 = wc * 8 + nt;
            short8 bf_ = *(const short8*)&w1p[(size_t)((ks * 16 + nt2) * 64 + l) * 8];
            acc[0][nt] = __builtin_amdgcn_mfma_f32_16x16x32_bf16(af[0], bf_, acc[0][nt], 0, 0, 0);
            acc[1][nt] = __builtin_amdgcn_mfma_f32_16x16x32_bf16(af[1], bf_, acc[1][nt], 0, 0, 0);
        }
    }
#pragma unroll
    for (int rt = 0; rt < 2; ++rt) {
        int rbase = r0 + rt * 16 + l4 * 4;
#pragma unroll
        for (int nt = 0; nt < 8; ++nt) {
            int col = wc * 128 + nt * 16 + l15;
            f32x4 c = acc[rt][nt];
#pragma unroll
            for (int r = 0; r < 4; ++r) {
                int row = rbase + r;
                if (row < N_NODES) xp1b[(size_t)row * D1 + col] = f2bf(c[r]);
            }
        }
    }
#pragma unroll
    for (int hl = 0; hl < 4; ++hl) {
        int hg = wc * 4 + hl;
        float as0 = a1s[hg * NC + l15], as1 = a1s[hg * NC + 16 + l15];
        float ad0 = a1d[hg * NC + l15], ad1 = a1d[hg * NC + 16 + l15];
#pragma unroll
        for (int rt = 0; rt < 2; ++rt) {
            f32x4 c0 = acc[rt][2 * hl], c1 = acc[rt][2 * hl + 1];
#pragma unroll
            for (int r = 0; r < 4; ++r) {
                float ss = c0[r] * as0 + c1[r] * as1;
                float dd = c0[r] * ad0 + c1[r] * ad1;
#pragma unroll
                for (int msk = 1; msk < 16; msk <<= 1) {
                    ss += __shfl_xor(ss, msk);
                    dd += __shfl_xor(dd, msk);
                }
                int row = r0 + rt * 16 + l4 * 4 + r;
                if (l15 == 0 && row < N_NODES) {
                    al1s[row * NH + hg] = ss;
                    al1d[row * NH + hg] = dd;
                }
            }
        }
    }
}

// ---- scatter edges to bin-grouped array via LDS cursors ----------------------
__global__ __launch_bounds__(256) void k_binscatter(const int* __restrict__ ei,
                                                    const int* __restrict__ offs,
                                                    const int* __restrict__ binBase,
                                                    int* __restrict__ binned) {
    __shared__ int cur[NBIN];
    int c = blockIdx.x;
    for (int b = threadIdx.x; b < NBIN; b += 256)
        cur[b] = binBase[b] + offs[b * NCHUNK + c];
    __syncthreads();
    int e0 = c * E_CHUNK;
    int e1 = e0 + E_CHUNK; if (e1 > N_EDGES) e1 = N_EDGES;
    for (int e = e0 + threadIdx.x; e < e1; e += 256) {
        int s = ei[e], d = ei[N_EDGES + e];
        int pos = atomicAdd(&cur[d >> 8], 1);
        binned[pos] = s | ((d & 255) << 16);   // src < 65536
    }
}

// ---- per-bin CSR finalize (rowptr/cnt/esrc incl. self-loops) -----------------
__global__ __launch_bounds__(256) void k_bincsr(const int* __restrict__ binBase,
                                                const int* __restrict__ binned,
                                                int* __restrict__ rowptr,
                                                int* __restrict__ cnt,
                                                int* __restrict__ esrc) {
    __shared__ int lcnt[256];
    __shared__ int sh[256];
    __shared__ int lcur[256];
    int b = blockIdx.x;
    int t = threadIdx.x;
    int estart = binBase[b];
    int eend = (b == NBIN - 1) ? N_EDGES : binBase[b + 1];
    int nbase = b * 256;
    int nin = N_NODES - nbase; if (nin > 256) nin = 256;
    lcnt[t] = 0;
    __syncthreads();
    for (int e = estart + t; e < eend; e += 256)
        atomicAdd(&lcnt[(binned[e] >> 16) & 255], 1);
    __syncthreads();
    int myc = lcnt[t] + (t < nin ? 1 : 0);   // + self loop
    sh[t] = myc;
    __syncthreads();
    for (int d = 1; d < 256; d <<= 1) {
        int v = (t >= d) ? sh[t - d] : 0;
        __syncthreads();
        sh[t] += v;
        __syncthreads();
    }
    int excl = sh[t] - myc;
    int outbase = estart + nbase;            // earlier bins' self-loops = nbase
    int rp = outbase + excl;
    if (t < nin) {
        rowptr[nbase + t] = rp;
        cnt[nbase + t] = myc;
        esrc[rp] = nbase + t;                // self-loop in slot 0
    }
    lcur[t] = rp + (t < nin ? 1 : 0);
    __syncthreads();
    for (int e = estart + t; e < eend; e += 256) {
        int v = binned[e];
        int pos = atomicAdd(&lcur[(v >> 16) & 255], 1);
        esrc[pos] = v & 0xFFFF;
    }
}

// ---------------- attention layer 1 (wave per dst node) -----------------------
__global__ __launch_bounds__(256) void k_att1(
    const unsigned short* __restrict__ xp1b, const float* __restrict__ al1s,
    const float* __restrict__ al1d, const float* __restrict__ b1,
    const int* __restrict__ rowptr, const int* __restrict__ cnt,
    const int* __restrict__ esrc, unsigned short* __restrict__ h1b) {
    __shared__ int s_src[4][64];
    __shared__ float s_alpha[4][64 * 8];
    int wv = threadIdx.x >> 6;
    int lane = threadIdx.x & 63;
    int n = blockIdx.x * 4 + wv;          // grid exactly covers 50000 = 12500*4
    int start = rowptr[n];
    int deg = cnt[n];
    int dcap = deg < 64 ? deg : 64;
    for (int j = lane; j < dcap; j += 64) s_src[wv][j] = esrc[start + j];
    int h = lane & 7, eg = lane >> 3;
    float ald = al1d[n * NH + h];
    float m = -1e30f, den = 0.f;
    for (int j = eg; j < dcap; j += 8) {
        int s = s_src[wv][j];
        float v = al1s[s * NH + h] + ald;
        v = v > 0.f ? v : NEG * v;
        s_alpha[wv][j * 8 + h] = v;
        if (v > m) { den = den * __expf(m - v) + 1.f; m = v; }
        else den += __expf(v - m);
    }
    for (int j = 64 + eg; j < deg; j += 8) {      // rare tail
        int s = esrc[start + j];
        float v = al1s[s * NH + h] + ald;
        v = v > 0.f ? v : NEG * v;
        if (v > m) { den = den * __expf(m - v) + 1.f; m = v; }
        else den += __expf(v - m);
    }
    for (int msk = 8; msk < 64; msk <<= 1) {
        float mo = __shfl_xor(m, msk), dn = __shfl_xor(den, msk);
        float nm = fmaxf(m, mo);
        den = den * __expf(m - nm) + dn * __expf(mo - nm);
        m = nm;
    }
    float rden1 = 1.f / den;
    for (int j = eg; j < dcap; j += 8) {
        float v = s_alpha[wv][j * 8 + h];
        s_alpha[wv][j * 8 + h] = __expf(v - m) * rden1;
    }
    // pass 2: full-wave per edge; lane owns 4 channels; 8 edges in flight
    int hh = lane >> 3;
    int cb = lane << 2;
    float m2 = __shfl(m, hh);
    float rd2 = __shfl(rden1, hh);
    float ald2 = al1d[n * NH + hh];
    float a0 = 0.f, a1 = 0.f, a2 = 0.f, a3 = 0.f;
    for (int j0 = 0; j0 < dcap; j0 += 8) {
        const unsigned short* p[8];
        float aw[8];
#pragma unroll
        for (int k = 0; k < 8; ++k) {
            int e = j0 + k;
            bool act = e < dcap;
            int ee = act ? e : 0;
            int s = s_src[wv][ee];
            aw[k] = act ? s_alpha[wv][ee * 8 + hh] : 0.f;
            p[k] = xp1b + (size_t)s * D1 + cb;
        }
#pragma unroll
        for (int k = 0; k < 8; ++k) {
            u16x4 xv = *(const u16x4*)p[k];
            a0 = fmaf(aw[k], bf2f(xv[0]), a0);
            a1 = fmaf(aw[k], bf2f(xv[1]), a1);
            a2 = fmaf(aw[k], bf2f(xv[2]), a2);
            a3 = fmaf(aw[k], bf2f(xv[3]), a3);
        }
    }
    for (int j = 64; j < deg; ++j) {      // rare tail
        int s = esrc[start + j];
        float v = al1s[s * NH + hh] + ald2;
        v = v > 0.f ? v : NEG * v;
        float al = __expf(v - m2) * rd2;
        u16x4 xv = *(const u16x4*)(xp1b + (size_t)s * D1 + cb);
        a0 = fmaf(al, bf2f(xv[0]), a0);
        a1 = fmaf(al, bf2f(xv[1]), a1);
        a2 = fmaf(al, bf2f(xv[2]), a2);
        a3 = fmaf(al, bf2f(xv[3]), a3);
    }
    float4 bb = *(const float4*)(b1 + cb);
    a0 += bb.x; a1 += bb.y; a2 += bb.z; a3 += bb.w;
    a0 = a0 > 0.f ? a0 : expm1f(a0);
    a1 = a1 > 0.f ? a1 : expm1f(a1);
    a2 = a2 > 0.f ? a2 : expm1f(a2);
    a3 = a3 > 0.f ? a3 : expm1f(a3);
    u16x4 pk = { f2bf(a0), f2bf(a1), f2bf(a2), f2bf(a3) };
    *(u16x4*)(h1b + (size_t)n * D1 + cb) = pk;
}

// ---------------- GEMM2 (bf16 h1 in, broadcast W2) + al2 epilogue -------------
__global__ __launch_bounds__(256) void k_gemm2(
    const unsigned short* __restrict__ h1b, const float* __restrict__ W2,
    const float* __restrict__ a2s, const float* __restrict__ a2d,
    float* __restrict__ xp2, float* __restrict__ al2s, float* __restrict__ al2d) {
    __shared__ float w2s[D1 * NCLS];
    for (int i = threadIdx.x; i < D1 * NCLS; i += 256) w2s[i] = W2[i];
    __syncthreads();
    int n = blockIdx.x * 256 + threadIdx.x;
    if (n >= N_NODES) return;
    float4 acc[4];
#pragma unroll
    for (int q = 0; q < 4; ++q) acc[q] = make_float4(0.f, 0.f, 0.f, 0.f);
    const unsigned short* hr = h1b + (size_t)n * D1;
    for (int k0 = 0; k0 < D1; k0 += 8) {
        u16x8 hv = *(const u16x8*)(hr + k0);
#pragma unroll
        for (int j = 0; j < 8; ++j) {
            float hx = bf2f(hv[j]);
#pragma unroll
            for (int q = 0; q < 4; ++q) {
                float4 w = *(const float4*)(&w2s[(k0 + j) * NCLS + q * 4]);
                acc[q].x = fmaf(hx, w.x, acc[q].x);
                acc[q].y = fmaf(hx, w.y, acc[q].y);
                acc[q].z = fmaf(hx, w.z, acc[q].z);
                acc[q].w = fmaf(hx, w.w, acc[q].w);
            }
        }
    }
    float ss = 0.f, dd = 0.f;
#pragma unroll
    for (int q = 0; q < 4; ++q) {
        *(float4*)(xp2 + (size_t)n * NCLS + q * 4) = acc[q];
        float4 s4 = *(const float4*)(a2s + q * 4);
        float4 d4 = *(const float4*)(a2d + q * 4);
        ss += acc[q].x * s4.x + acc[q].y * s4.y + acc[q].z * s4.z + acc[q].w * s4.w;
        dd += acc[q].x * d4.x + acc[q].y * d4.y + acc[q].z * d4.z + acc[q].w * d4.w;
    }
    al2s[n] = ss;
    al2d[n] = dd;
}

// ---------------- attention layer 2 (wave per dst node) -----------------------
__global__ __launch_bounds__(256) void k_att2(
    const float* __restrict__ xp2, const float* __restrict__ al2s,
    const float* __restrict__ al2d, const float* __restrict__ b2,
    const int* __restrict__ rowptr, const int* __restrict__ cnt,
    const int* __restrict__ esrc, float* __restrict__ out2) {
    __shared__ int s_src[4][64];
    __shared__ float s_a[4][64];
    int wave = threadIdx.x >> 6;
    int lane = threadIdx.x & 63;
    int n = blockIdx.x * 4 + wave;
    int start = rowptr[n];
    int deg = cnt[n];
    int dcap = deg < 64 ? deg : 64;
    float ald = al2d[n];
    float m = -1e30f, den = 0.f;
    for (int j = lane; j < dcap; j += 64) {
        int s = esrc[start + j];
        s_src[wave][j] = s;
        float v = al2s[s] + ald;
        v = v > 0.f ? v : NEG * v;
        s_a[wave][j] = v;
        if (v > m) { den = den * __expf(m - v) + 1.f; m = v; }
        else den += __expf(v - m);
    }
    for (int j = 64 + lane; j < deg; j += 64) {   // rare tail
        float v = al2s[esrc[start + j]] + ald;
        v = v > 0.f ? v : NEG * v;
        if (v > m) { den = den * __expf(m - v) + 1.f; m = v; }
        else den += __expf(v - m);
    }
    for (int msk = 1; msk < 64; msk <<= 1) {
        float mo = __shfl_xor(m, msk), dn = __shfl_xor(den, msk);
        float nm = fmaxf(m, mo);
        den = den * __expf(m - nm) + dn * __expf(mo - nm);
        m = nm;
    }
    float rden = 1.f / den;
    for (int j = lane; j < dcap; j += 64)
        s_a[wave][j] = __expf(s_a[wave][j] - m) * rden;
    int c = lane & 15;
    int eg = lane >> 4;                   // 4 edges x 16 channels, 2-deep unroll
    float acc = 0.f;
    for (int j0 = 0; j0 < dcap; j0 += 8) {
        const float* p[2];
        float aw[2];
#pragma unroll
        for (int k = 0; k < 2; ++k) {
            int e = j0 + eg + 4 * k;
            bool act = e < dcap;
            int ee = act ? e : 0;
            aw[k] = act ? s_a[wave][ee] : 0.f;
            p[k] = xp2 + (size_t)s_src[wave][ee] * NCLS + c;
        }
        acc = fmaf(aw[0], p[0][0], acc);
        acc = fmaf(aw[1], p[1][0], acc);
    }
    for (int j = 64 + eg; j < deg; j += 4) {      // rare tail
        int s = esrc[start + j];
        float v = al2s[s] + ald;
        v = v > 0.f ? v : NEG * v;
        acc += __expf(v - m) * rden * xp2[(size_t)s * NCLS + c];
    }
    acc += __shfl_xor(acc, 16);
    acc += __shfl_xor(acc, 32);
    if (lane < 16) out2[(size_t)n * NCLS + lane] = acc + b2[lane];
}

// ---------------- pooling (LDS pre-aggregation, sorted batch) -----------------
__global__ __launch_bounds__(256) void k_pool(
    const float* __restrict__ out2, const int* __restrict__ batch,
    float* __restrict__ poolS, float* __restrict__ poolC) {
    __shared__ float sacc[NGRP * NCLS];
    __shared__ float scnt[NGRP];
    for (int i = threadIdx.x; i < NGRP * NCLS; i += 256) sacc[i] = 0.f;
    if (threadIdx.x < NGRP) scnt[threadIdx.x] = 0.f;
    __syncthreads();
    int n = blockIdx.x * 256 + threadIdx.x;
    if (n < N_NODES) {
        int g = batch[n];
        atomicAdd(&scnt[g], 1.f);
#pragma unroll
        for (int q = 0; q < 4; ++q) {
            float4 v = *(const float4*)(out2 + (size_t)n * NCLS + q * 4);
            atomicAdd(&sacc[g * NCLS + q * 4 + 0], v.x);
            atomicAdd(&sacc[g * NCLS + q * 4 + 1], v.y);
            atomicAdd(&sacc[g * NCLS + q * 4 + 2], v.z);
            atomicAdd(&sacc[g * NCLS + q * 4 + 3], v.w);
        }
    }
    __syncthreads();
    for (int i = threadIdx.x; i < NGRP * NCLS; i += 256)
        if (sacc[i] != 0.f) atomicAdd(&poolS[i], sacc[i]);
    if (threadIdx.x < NGRP && scnt[threadIdx.x] != 0.f)
        atomicAdd(&poolC[threadIdx.x], scnt[threadIdx.x]);
}

__global__ void k_final(const float* __restrict__ poolS,
                        const float* __restrict__ poolC, float* __restrict__ out) {
    int g = threadIdx.x;
    if (g >= NGRP) return;
    float inv = 1.f / fmaxf(poolC[g], 1.f);
    float v[NCLS];
    float m = -1e30f;
#pragma unroll
    for (int c = 0; c < NCLS; ++c) {
        v[c] = poolS[g * NCLS + c] * inv;
        m = fmaxf(m, v[c]);
    }
    float s = 0.f;
#pragma unroll
    for (int c = 0; c < NCLS; ++c) s += expf(v[c] - m);
    float lse = m + logf(s);
#pragma unroll
    for (int c = 0; c < NCLS; ++c) out[g * NCLS + c] = v[c] - lse;
}

extern "C" void kernel_launch(void* const* d_in, const int* in_sizes, int n_in,
                              void* d_out, int out_size, void* d_ws, size_t ws_size,
                              hipStream_t stream) {
    const float* x    = (const float*)d_in[0];
    const int*   ei   = (const int*)d_in[1];
    const int*   batch = (const int*)d_in[2];
    const float* W1   = (const float*)d_in[3];
    const float* a1s  = (const float*)d_in[4];
    const float* a1d  = (const float*)d_in[5];
    const float* b1   = (const float*)d_in[6];
    const float* W2   = (const float*)d_in[7];
    const float* a2s  = (const float*)d_in[8];
    const float* a2d  = (const float*)d_in[9];
    const float* b2   = (const float*)d_in[10];
    float* out = (float*)d_out;

    float* f = (float*)d_ws;
    float* al1s_ = f;  f += (size_t)N_NODES * NH;
    float* al1d_ = f;  f += (size_t)N_NODES * NH;
    float* xp2   = f;  f += (size_t)N_NODES * NCLS;
    float* al2s_ = f;  f += N_NODES;
    float* al2d_ = f;  f += N_NODES;
    float* out2  = f;  f += (size_t)N_NODES * NCLS;
    float* poolS = f;  f += NGRP * NCLS;
    float* poolC = f;  f += NGRP;
    unsigned short* xp1b = (unsigned short*)f;
    unsigned short* h1b  = xp1b + (size_t)N_NODES * D1;
    unsigned short* w1p  = h1b + (size_t)N_NODES * D1;
    int* binmat  = (int*)(w1p + FDIM * D1);
    int* binTot  = binmat + NBIN * NCHUNK;
    int* binBase = binTot + NBIN;
    int* binned  = binBase + NBIN;
    int* rowptr  = binned + N_EDGES;
    int* cnt     = rowptr + N_NODES;
    int* esrc    = cnt + N_NODES;

    k_init<<<NB_N, 256, 0, stream>>>(W1, w1p, poolS, poolC, ei, binmat);
    k_binprescan<<<NBIN, 256, 0, stream>>>(binmat, binTot);
    k_basescan<<<1, 256, 0, stream>>>(binTot, binBase);
    k_gemm1m<<<G1_BLOCKS, 256, 0, stream>>>(x, w1p, a1s, a1d, xp1b, al1s_, al1d_);
    k_binscatter<<<NCHUNK, 256, 0, stream>>>(ei, binmat, binBase, binned);
    k_bincsr<<<NBIN, 256, 0, stream>>>(binBase, binned, rowptr, cnt, esrc);
    k_att1<<<N_NODES / 4, 256, 0, stream>>>(xp1b, al1s_, al1d_, b1, rowptr, cnt, esrc, h1b);
    k_gemm2<<<NB_N, 256, 0, stream>>>(h1b, W2, a2s, a2d, xp2, al2s_, al2d_);
    k_att2<<<N_NODES / 4, 256, 0, stream>>>(xp2, al2s_, al2d_, b2, rowptr, cnt, esrc, out2);
    k_pool<<<NB_N, 256, 0, stream>>>(out2, batch, poolS, poolC);
    k_final<<<1, 64, 0, stream>>>(poolS, poolC, out);
}

// Round 11
// 192.654 us; speedup vs baseline: 1.8356x; 1.0040x over previous
//
#include <hip/hip_runtime.h>
#include <math.h>

#define N_NODES 50000
#define N_EDGES 800000
#define FDIM 128
#define NH 8
#define NC 32
#define D1 256      // NH*NC
#define NCLS 16
#define NGRP 64
#define NEG 0.2f
#define E_TOT (N_EDGES + N_NODES)
#define NB_N 196        // (N_NODES+255)/256
#define G1_BLOCKS 782   // (N_NODES+63)/64
#define E_CHUNK 4096
#define NCHUNK 196      // ceil(800000/4096)
#define NBIN 196        // ceil(50000/256)

typedef __attribute__((ext_vector_type(8))) unsigned short u16x8;
typedef __attribute__((ext_vector_type(4))) unsigned short u16x4;
typedef __attribute__((ext_vector_type(8))) short short8;
typedef __attribute__((ext_vector_type(4))) float f32x4;

static __device__ __forceinline__ float bf2f(unsigned short u) {
    return __uint_as_float(((unsigned int)u) << 16);
}
static __device__ __forceinline__ unsigned short f2bf(float f) {
    unsigned int b = __float_as_uint(f);
    return (unsigned short)((b + 0x7FFFu + ((b >> 16) & 1u)) >> 16);
}

// ---- init (pool zero + W1 pack) FUSED with per-chunk bin histogram -----------
__global__ __launch_bounds__(256) void k_init(
    const float* __restrict__ W1, unsigned short* __restrict__ w1p,
    float* __restrict__ poolS, float* __restrict__ poolC,
    const int* __restrict__ ei, int* __restrict__ binmat) {
    __shared__ int h[NBIN];
    int c = blockIdx.x;
    for (int b = threadIdx.x; b < NBIN; b += 256) h[b] = 0;
    __syncthreads();
    int e0 = c * E_CHUNK;
    int e1 = e0 + E_CHUNK; if (e1 > N_EDGES) e1 = N_EDGES;
    for (int e = e0 + threadIdx.x; e < e1; e += 256)
        atomicAdd(&h[ei[N_EDGES + e] >> 8], 1);
    // independent init work while histogram atomics settle
    int i = blockIdx.x * 256 + threadIdx.x;
    if (i < NGRP * NCLS) poolS[i] = 0.f;
    if (i < NGRP) poolC[i] = 0.f;
    if (i < FDIM * D1) {
        int ks = i >> 13;
        int r = i & 8191;
        int nt2 = r >> 9;
        int r2 = r & 511;
        int lane = r2 >> 3, e = r2 & 7;
        int k = ks * 32 + (lane >> 4) * 8 + e;
        int col = nt2 * 16 + (lane & 15);
        w1p[i] = f2bf(W1[k * D1 + col]);
    }
    __syncthreads();
    for (int b = threadIdx.x; b < NBIN; b += 256) binmat[b * NCHUNK + c] = h[b];
}

// ---- per-bin row scan: binmat[b][*] -> exclusive within-row prefix + total ---
__global__ __launch_bounds__(256) void k_binprescan(int* __restrict__ binmat,
                                                    int* __restrict__ binTot) {
    __shared__ int sh[256];
    int b = blockIdx.x, t = threadIdx.x;
    int v = (t < NCHUNK) ? binmat[b * NCHUNK + t] : 0;
    sh[t] = v;
    __syncthreads();
    for (int d = 1; d < 256; d <<= 1) {
        int tv = (t >= d) ? sh[t - d] : 0;
        __syncthreads();
        sh[t] += tv;
        __syncthreads();
    }
    if (t < NCHUNK) binmat[b * NCHUNK + t] = sh[t] - v;   // exclusive in-row
    if (t == 255) binTot[b] = sh[255];
}

// ------ GEMM1 via MFMA bf16 (no LDS): xp1b = bf16(x)@bf16(W1), fused al1 ------
__global__ __launch_bounds__(256) void k_gemm1m(
    const float* __restrict__ x, const unsigned short* __restrict__ w1p,
    const float* __restrict__ a1s, const float* __restrict__ a1d,
    unsigned short* __restrict__ xp1b, float* __restrict__ al1s,
    float* __restrict__ al1d) {
    const int l = threadIdx.x & 63;
    const int wid = threadIdx.x >> 6;
    const int wr = wid >> 1, wc = wid & 1;
    const int l15 = l & 15, l4 = l >> 4;
    const int base = blockIdx.x * 64;
    const int r0 = base + wr * 32;

    f32x4 acc[2][8] = {};
#pragma unroll
    for (int ks = 0; ks < 4; ++ks) {
        const int kk = ks * 32 + l4 * 8;
        short8 af[2];
#pragma unroll
        for (int rt = 0; rt < 2; ++rt) {
            int row = r0 + rt * 16 + l15;
            float4 v0 = make_float4(0.f, 0.f, 0.f, 0.f), v1 = v0;
            if (row < N_NODES) {
                const float* xr = x + (size_t)row * FDIM + kk;
                v0 = *(const float4*)xr;
                v1 = *(const float4*)(xr + 4);
            }
            short8 a;
            a[0] = (short)f2bf(v0.x); a[1] = (short)f2bf(v0.y);
            a[2] = (short)f2bf(v0.z); a[3] = (short)f2bf(v0.w);
            a[4] = (short)f2bf(v1.x); a[5] = (short)f2bf(v1.y);
            a[6] = (short)f2bf(v1.z); a[7] = (short)f2bf(v1.w);
            af[rt] = a;
        }
#pragma unroll
        for (int nt = 0; nt < 8; ++nt) {
            int nt2 = wc * 8 + nt;
            short8 bf_ = *(const short8*)&w1p[(size_t)((ks * 16 + nt2) * 64 + l) * 8];
            acc[0][nt] = __builtin_amdgcn_mfma_f32_16x16x32_bf16(af[0], bf_, acc[0][nt], 0, 0, 0);
            acc[1][nt] = __builtin_amdgcn_mfma_f32_16x16x32_bf16(af[1], bf_, acc[1][nt], 0, 0, 0);
        }
    }
#pragma unroll
    for (int rt = 0; rt < 2; ++rt) {
        int rbase = r0 + rt * 16 + l4 * 4;
#pragma unroll
        for (int nt = 0; nt < 8; ++nt) {
            int col = wc * 128 + nt * 16 + l15;
            f32x4 c = acc[rt][nt];
#pragma unroll
            for (int r = 0; r < 4; ++r) {
                int row = rbase + r;
                if (row < N_NODES) xp1b[(size_t)row * D1 + col] = f2bf(c[r]);
            }
        }
    }
#pragma unroll
    for (int hl = 0; hl < 4; ++hl) {
        int hg = wc * 4 + hl;
        float as0 = a1s[hg * NC + l15], as1 = a1s[hg * NC + 16 + l15];
        float ad0 = a1d[hg * NC + l15], ad1 = a1d[hg * NC + 16 + l15];
#pragma unroll
        for (int rt = 0; rt < 2; ++rt) {
            f32x4 c0 = acc[rt][2 * hl], c1 = acc[rt][2 * hl + 1];
#pragma unroll
            for (int r = 0; r < 4; ++r) {
                float ss = c0[r] * as0 + c1[r] * as1;
                float dd = c0[r] * ad0 + c1[r] * ad1;
#pragma unroll
                for (int msk = 1; msk < 16; msk <<= 1) {
                    ss += __shfl_xor(ss, msk);
                    dd += __shfl_xor(dd, msk);
                }
                int row = r0 + rt * 16 + l4 * 4 + r;
                if (l15 == 0 && row < N_NODES) {
                    al1s[row * NH + hg] = ss;
                    al1d[row * NH + hg] = dd;
                }
            }
        }
    }
}

// ---- scatter edges to bin-grouped array via LDS cursors (scan binTot inline) -
__global__ __launch_bounds__(256) void k_binscatter(const int* __restrict__ ei,
                                                    const int* __restrict__ offs,
                                                    const int* __restrict__ binTot,
                                                    int* __restrict__ binned) {
    __shared__ int cur[NBIN];
    __shared__ int sb[256];
    int c = blockIdx.x;
    int t = threadIdx.x;
    int v = (t < NBIN) ? binTot[t] : 0;
    sb[t] = v;
    __syncthreads();
    for (int d = 1; d < 256; d <<= 1) {
        int tv = (t >= d) ? sb[t - d] : 0;
        __syncthreads();
        sb[t] += tv;
        __syncthreads();
    }
    if (t < NBIN) cur[t] = (sb[t] - v) + offs[t * NCHUNK + c];
    __syncthreads();
    int e0 = c * E_CHUNK;
    int e1 = e0 + E_CHUNK; if (e1 > N_EDGES) e1 = N_EDGES;
    for (int e = e0 + t; e < e1; e += 256) {
        int s = ei[e], d = ei[N_EDGES + e];
        int pos = atomicAdd(&cur[d >> 8], 1);
        binned[pos] = s | ((d & 255) << 16);   // src < 65536
    }
}

// ---- per-bin CSR finalize (scan binTot inline) -------------------------------
__global__ __launch_bounds__(256) void k_bincsr(const int* __restrict__ binTot,
                                                const int* __restrict__ binned,
                                                int* __restrict__ rowptr,
                                                int* __restrict__ cnt,
                                                int* __restrict__ esrc) {
    __shared__ int sh[256];
    __shared__ int lcnt[256];
    __shared__ int lcur[256];
    int b = blockIdx.x;
    int t = threadIdx.x;
    int v = (t < NBIN) ? binTot[t] : 0;
    sh[t] = v;
    __syncthreads();
    for (int d = 1; d < 256; d <<= 1) {
        int tv = (t >= d) ? sh[t - d] : 0;
        __syncthreads();
        sh[t] += tv;
        __syncthreads();
    }
    int estart = (b == 0) ? 0 : sh[b - 1];
    int eend = sh[b];
    __syncthreads();
    int nbase = b * 256;
    int nin = N_NODES - nbase; if (nin > 256) nin = 256;
    lcnt[t] = 0;
    __syncthreads();
    for (int e = estart + t; e < eend; e += 256)
        atomicAdd(&lcnt[(binned[e] >> 16) & 255], 1);
    __syncthreads();
    int myc = lcnt[t] + (t < nin ? 1 : 0);   // + self loop
    sh[t] = myc;
    __syncthreads();
    for (int d = 1; d < 256; d <<= 1) {
        int tv = (t >= d) ? sh[t - d] : 0;
        __syncthreads();
        sh[t] += tv;
        __syncthreads();
    }
    int excl = sh[t] - myc;
    int outbase = estart + nbase;            // earlier bins' self-loops = nbase
    int rp = outbase + excl;
    if (t < nin) {
        rowptr[nbase + t] = rp;
        cnt[nbase + t] = myc;
        esrc[rp] = nbase + t;                // self-loop in slot 0
    }
    lcur[t] = rp + (t < nin ? 1 : 0);
    __syncthreads();
    for (int e = estart + t; e < eend; e += 256) {
        int vv = binned[e];
        int pos = atomicAdd(&lcur[(vv >> 16) & 255], 1);
        esrc[pos] = vv & 0xFFFF;
    }
}

// -------- attention layer 1 (wave per dst node, mask-free padded pass 2) ------
__global__ __launch_bounds__(256) void k_att1(
    const unsigned short* __restrict__ xp1b, const float* __restrict__ al1s,
    const float* __restrict__ al1d, const float* __restrict__ b1,
    const int* __restrict__ rowptr, const int* __restrict__ cnt,
    const int* __restrict__ esrc, unsigned short* __restrict__ h1b) {
    __shared__ int s_src[4][64];
    __shared__ float s_alpha[4][64 * 8];
    int wv = threadIdx.x >> 6;
    int lane = threadIdx.x & 63;
    int n = blockIdx.x * 4 + wv;          // grid exactly covers 50000 = 12500*4
    int start = rowptr[n];
    int deg = cnt[n];
    int dcap = deg < 64 ? deg : 64;
    int dpad = (dcap + 7) & ~7;
    for (int j = lane; j < dpad; j += 64)
        s_src[wv][j] = (j < dcap) ? esrc[start + j] : n;   // pad with self (hot)
    int npad = (dpad - dcap) * 8;
    if (lane < npad) s_alpha[wv][dcap * 8 + lane] = 0.f;   // zero pad alphas
    // pass 1a: leaky logits into LDS + per-(head,edge-group) max
    int h = lane & 7, eg = lane >> 3;
    float ald = al1d[n * NH + h];
    float m = -1e30f;
    for (int j = eg; j < dcap; j += 8) {
        int s = s_src[wv][j];
        float v = al1s[s * NH + h] + ald;
        v = fmaxf(v, NEG * v);                  // leaky relu (NEG<1)
        s_alpha[wv][j * 8 + h] = v;
        m = fmaxf(m, v);
    }
    if (deg > 64) {
        for (int j = 64 + eg; j < deg; j += 8) {
            int s = esrc[start + j];
            float v = al1s[s * NH + h] + ald;
            m = fmaxf(m, fmaxf(v, NEG * v));
        }
    }
    for (int msk = 8; msk < 64; msk <<= 1) m = fmaxf(m, __shfl_xor(m, msk));
    // pass 1b: single exp per (edge,head); den accumulate; alphas UNNORMALIZED
    float den = 0.f;
    for (int j = eg; j < dcap; j += 8) {
        float e = __expf(s_alpha[wv][j * 8 + h] - m);
        s_alpha[wv][j * 8 + h] = e;
        den += e;
    }
    if (deg > 64) {
        for (int j = 64 + eg; j < deg; j += 8) {
            int s = esrc[start + j];
            float v = al1s[s * NH + h] + ald;
            v = fmaxf(v, NEG * v);
            den += __expf(v - m);
        }
    }
    for (int msk = 8; msk < 64; msk <<= 1) den += __shfl_xor(den, msk);
    // pass 2: full-wave per edge; lane owns 4 channels; 8 edges, no masks
    int hh = lane >> 3;
    int cbb = lane << 3;                       // byte offset of lane's channels
    float rd2 = 1.f / __shfl(den, hh);
    float m2 = __shfl(m, hh);
    float a0 = 0.f, a1 = 0.f, a2 = 0.f, a3 = 0.f;
    for (int j0 = 0; j0 < dpad; j0 += 8) {
        int off[8];
        float aw[8];
#pragma unroll
        for (int k = 0; k < 8; ++k) {
            int s = s_src[wv][j0 + k];
            aw[k] = s_alpha[wv][(j0 + k) * 8 + hh];
            off[k] = (s << 9) + cbb;           // s*512B + lane*8B
        }
#pragma unroll
        for (int k = 0; k < 8; ++k) {
            u16x4 xv = *(const u16x4*)((const char*)xp1b + off[k]);
            a0 = fmaf(aw[k], bf2f(xv[0]), a0);
            a1 = fmaf(aw[k], bf2f(xv[1]), a1);
            a2 = fmaf(aw[k], bf2f(xv[2]), a2);
            a3 = fmaf(aw[k], bf2f(xv[3]), a3);
        }
    }
    if (deg > 64) {
        float ald2 = al1d[n * NH + hh];
        for (int j = 64; j < deg; ++j) {
            int s = esrc[start + j];
            float v = al1s[s * NH + hh] + ald2;
            v = fmaxf(v, NEG * v);
            float al = __expf(v - m2);          // unnormalized
            u16x4 xv = *(const u16x4*)((const char*)xp1b + (s << 9) + cbb);
            a0 = fmaf(al, bf2f(xv[0]), a0);
            a1 = fmaf(al, bf2f(xv[1]), a1);
            a2 = fmaf(al, bf2f(xv[2]), a2);
            a3 = fmaf(al, bf2f(xv[3]), a3);
        }
    }
    // epilogue: normalize once, bias, ELU, bf16 store
    int cb = lane << 2;
    float4 bb = *(const float4*)(b1 + cb);
    a0 = fmaf(a0, rd2, bb.x);
    a1 = fmaf(a1, rd2, bb.y);
    a2 = fmaf(a2, rd2, bb.z);
    a3 = fmaf(a3, rd2, bb.w);
    a0 = a0 > 0.f ? a0 : expm1f(a0);
    a1 = a1 > 0.f ? a1 : expm1f(a1);
    a2 = a2 > 0.f ? a2 : expm1f(a2);
    a3 = a3 > 0.f ? a3 : expm1f(a3);
    u16x4 pk = { f2bf(a0), f2bf(a1), f2bf(a2), f2bf(a3) };
    *(u16x4*)(h1b + (size_t)n * D1 + cb) = pk;
}

// ---------------- GEMM2 (bf16 h1 in, broadcast W2) + al2 epilogue -------------
__global__ __launch_bounds__(256) void k_gemm2(
    const unsigned short* __restrict__ h1b, const float* __restrict__ W2,
    const float* __restrict__ a2s, const float* __restrict__ a2d,
    float* __restrict__ xp2, float* __restrict__ al2s, float* __restrict__ al2d) {
    __shared__ float w2s[D1 * NCLS];
    for (int i = threadIdx.x; i < D1 * NCLS; i += 256) w2s[i] = W2[i];
    __syncthreads();
    int n = blockIdx.x * 256 + threadIdx.x;
    if (n >= N_NODES) return;
    float4 acc[4];
#pragma unroll
    for (int q = 0; q < 4; ++q) acc[q] = make_float4(0.f, 0.f, 0.f, 0.f);
    const unsigned short* hr = h1b + (size_t)n * D1;
    for (int k0 = 0; k0 < D1; k0 += 8) {
        u16x8 hv = *(const u16x8*)(hr + k0);
#pragma unroll
        for (int j = 0; j < 8; ++j) {
            float hx = bf2f(hv[j]);
#pragma unroll
            for (int q = 0; q < 4; ++q) {
                float4 w = *(const float4*)(&w2s[(k0 + j) * NCLS + q * 4]);
                acc[q].x = fmaf(hx, w.x, acc[q].x);
                acc[q].y = fmaf(hx, w.y, acc[q].y);
                acc[q].z = fmaf(hx, w.z, acc[q].z);
                acc[q].w = fmaf(hx, w.w, acc[q].w);
            }
        }
    }
    float ss = 0.f, dd = 0.f;
#pragma unroll
    for (int q = 0; q < 4; ++q) {
        *(float4*)(xp2 + (size_t)n * NCLS + q * 4) = acc[q];
        float4 s4 = *(const float4*)(a2s + q * 4);
        float4 d4 = *(const float4*)(a2d + q * 4);
        ss += acc[q].x * s4.x + acc[q].y * s4.y + acc[q].z * s4.z + acc[q].w * s4.w;
        dd += acc[q].x * d4.x + acc[q].y * d4.y + acc[q].z * d4.z + acc[q].w * d4.w;
    }
    al2s[n] = ss;
    al2d[n] = dd;
}

// -------- attention layer 2 (wave per dst node, mask-free padded pass 2) ------
__global__ __launch_bounds__(256) void k_att2(
    const float* __restrict__ xp2, const float* __restrict__ al2s,
    const float* __restrict__ al2d, const float* __restrict__ b2,
    const int* __restrict__ rowptr, const int* __restrict__ cnt,
    const int* __restrict__ esrc, float* __restrict__ out2) {
    __shared__ int s_src[4][64];
    __shared__ float s_a[4][64];
    int wave = threadIdx.x >> 6;
    int lane = threadIdx.x & 63;
    int n = blockIdx.x * 4 + wave;
    int start = rowptr[n];
    int deg = cnt[n];
    int dcap = deg < 64 ? deg : 64;
    int dpad = (dcap + 7) & ~7;
    for (int j = lane; j < dpad; j += 64)
        s_src[wave][j] = (j < dcap) ? esrc[start + j] : n;
    if (lane < dpad - dcap) s_a[wave][dcap + lane] = 0.f;
    float ald = al2d[n];
    float m = -1e30f;
    for (int j = lane; j < dcap; j += 64) {
        int s = s_src[wave][j];
        float v = al2s[s] + ald;
        v = fmaxf(v, NEG * v);
        s_a[wave][j] = v;
        m = fmaxf(m, v);
    }
    if (deg > 64) {
        for (int j = 64 + lane; j < deg; j += 64) {
            float v = al2s[esrc[start + j]] + ald;
            m = fmaxf(m, fmaxf(v, NEG * v));
        }
    }
    for (int msk = 1; msk < 64; msk <<= 1) m = fmaxf(m, __shfl_xor(m, msk));
    float den = 0.f;
    for (int j = lane; j < dcap; j += 64) {
        float e = __expf(s_a[wave][j] - m);
        s_a[wave][j] = e;
        den += e;
    }
    if (deg > 64) {
        for (int j = 64 + lane; j < deg; j += 64) {
            float v = al2s[esrc[start + j]] + ald;
            v = fmaxf(v, NEG * v);
            den += __expf(v - m);
        }
    }
    for (int msk = 1; msk < 64; msk <<= 1) den += __shfl_xor(den, msk);
    float rden = 1.f / den;
    int c = lane & 15;
    int eg = lane >> 4;                   // 4 edge slots x 16 channels
    float acc = 0.f;
    for (int j0 = 0; j0 < dpad; j0 += 8) {
#pragma unroll
        for (int k = 0; k < 2; ++k) {
            int e = j0 + eg + 4 * k;
            float aw = s_a[wave][e];
            int s = s_src[wave][e];
            acc = fmaf(aw, xp2[(size_t)s * NCLS + c], acc);
        }
    }
    if (deg > 64) {
        for (int j = 64 + eg; j < deg; j += 4) {
            int s = esrc[start + j];
            float v = al2s[s] + ald;
            v = fmaxf(v, NEG * v);
            acc += __expf(v - m) * xp2[(size_t)s * NCLS + c];
        }
    }
    acc += __shfl_xor(acc, 16);
    acc += __shfl_xor(acc, 32);
    if (lane < 16) out2[(size_t)n * NCLS + lane] = acc * rden + b2[lane];
}

// ---------------- pooling (LDS pre-aggregation, sorted batch) -----------------
__global__ __launch_bounds__(256) void k_pool(
    const float* __restrict__ out2, const int* __restrict__ batch,
    float* __restrict__ poolS, float* __restrict__ poolC) {
    __shared__ float sacc[NGRP * NCLS];
    __shared__ float scnt[NGRP];
    for (int i = threadIdx.x; i < NGRP * NCLS; i += 256) sacc[i] = 0.f;
    if (threadIdx.x < NGRP) scnt[threadIdx.x] = 0.f;
    __syncthreads();
    int n = blockIdx.x * 256 + threadIdx.x;
    if (n < N_NODES) {
        int g = batch[n];
        atomicAdd(&scnt[g], 1.f);
#pragma unroll
        for (int q = 0; q < 4; ++q) {
            float4 v = *(const float4*)(out2 + (size_t)n * NCLS + q * 4);
            atomicAdd(&sacc[g * NCLS + q * 4 + 0], v.x);
            atomicAdd(&sacc[g * NCLS + q * 4 + 1], v.y);
            atomicAdd(&sacc[g * NCLS + q * 4 + 2], v.z);
            atomicAdd(&sacc[g * NCLS + q * 4 + 3], v.w);
        }
    }
    __syncthreads();
    for (int i = threadIdx.x; i < NGRP * NCLS; i += 256)
        if (sacc[i] != 0.f) atomicAdd(&poolS[i], sacc[i]);
    if (threadIdx.x < NGRP && scnt[threadIdx.x] != 0.f)
        atomicAdd(&poolC[threadIdx.x], scnt[threadIdx.x]);
}

__global__ void k_final(const float* __restrict__ poolS,
                        const float* __restrict__ poolC, float* __restrict__ out) {
    int g = threadIdx.x;
    if (g >= NGRP) return;
    float inv = 1.f / fmaxf(poolC[g], 1.f);
    float v[NCLS];
    float m = -1e30f;
#pragma unroll
    for (int c = 0; c < NCLS; ++c) {
        v[c] = poolS[g * NCLS + c] * inv;
        m = fmaxf(m, v[c]);
    }
    float s = 0.f;
#pragma unroll
    for (int c = 0; c < NCLS; ++c) s += expf(v[c] - m);
    float lse = m + logf(s);
#pragma unroll
    for (int c = 0; c < NCLS; ++c) out[g * NCLS + c] = v[c] - lse;
}

extern "C" void kernel_launch(void* const* d_in, const int* in_sizes, int n_in,
                              void* d_out, int out_size, void* d_ws, size_t ws_size,
                              hipStream_t stream) {
    const float* x    = (const float*)d_in[0];
    const int*   ei   = (const int*)d_in[1];
    const int*   batch = (const int*)d_in[2];
    const float* W1   = (const float*)d_in[3];
    const float* a1s  = (const float*)d_in[4];
    const float* a1d  = (const float*)d_in[5];
    const float* b1   = (const float*)d_in[6];
    const float* W2   = (const float*)d_in[7];
    const float* a2s  = (const float*)d_in[8];
    const float* a2d  = (const float*)d_in[9];
    const float* b2   = (const float*)d_in[10];
    float* out = (float*)d_out;

    float* f = (float*)d_ws;
    float* al1s_ = f;  f += (size_t)N_NODES * NH;
    float* al1d_ = f;  f += (size_t)N_NODES * NH;
    float* xp2   = f;  f += (size_t)N_NODES * NCLS;
    float* al2s_ = f;  f += N_NODES;
    float* al2d_ = f;  f += N_NODES;
    float* out2  = f;  f += (size_t)N_NODES * NCLS;
    float* poolS = f;  f += NGRP * NCLS;
    float* poolC = f;  f += NGRP;
    unsigned short* xp1b = (unsigned short*)f;
    unsigned short* h1b  = xp1b + (size_t)N_NODES * D1;
    unsigned short* w1p  = h1b + (size_t)N_NODES * D1;
    int* binmat  = (int*)(w1p + FDIM * D1);
    int* binTot  = binmat + NBIN * NCHUNK;
    int* binned  = binTot + NBIN;
    int* rowptr  = binned + N_EDGES;
    int* cnt     = rowptr + N_NODES;
    int* esrc    = cnt + N_NODES;

    k_init<<<NB_N, 256, 0, stream>>>(W1, w1p, poolS, poolC, ei, binmat);
    k_binprescan<<<NBIN, 256, 0, stream>>>(binmat, binTot);
    k_gemm1m<<<G1_BLOCKS, 256, 0, stream>>>(x, w1p, a1s, a1d, xp1b, al1s_, al1d_);
    k_binscatter<<<NCHUNK, 256, 0, stream>>>(ei, binmat, binTot, binned);
    k_bincsr<<<NBIN, 256, 0, stream>>>(binTot, binned, rowptr, cnt, esrc);
    k_att1<<<N_NODES / 4, 256, 0, stream>>>(xp1b, al1s_, al1d_, b1, rowptr, cnt, esrc, h1b);
    k_gemm2<<<NB_N, 256, 0, stream>>>(h1b, W2, a2s, a2d, xp2, al2s_, al2d_);
    k_att2<<<N_NODES / 4, 256, 0, stream>>>(xp2, al2s_, al2d_, b2, rowptr, cnt, esrc, out2);
    k_pool<<<NB_N, 256, 0, stream>>>(out2, batch, poolS, poolC);
    k_final<<<1, 64, 0, stream>>>(poolS, poolC, out);
}

// Round 12
// 186.650 us; speedup vs baseline: 1.8946x; 1.0322x over previous
//
#include <hip/hip_runtime.h>
#include <math.h>

#define N_NODES 50000
#define N_EDGES 800000
#define FDIM 128
#define NH 8
#define NC 32
#define D1 256      // NH*NC
#define NCLS 16
#define NGRP 64
#define NEG 0.2f
#define E_TOT (N_EDGES + N_NODES)
#define NB_N 196        // (N_NODES+255)/256
#define G1_BLOCKS 782   // (N_NODES+63)/64
#define E_CHUNK 4096
#define NCHUNK 196      // ceil(800000/4096)
#define NBIN 196        // ceil(50000/256)

typedef __attribute__((ext_vector_type(4))) unsigned short u16x4;
typedef __attribute__((ext_vector_type(8))) short short8;
typedef __attribute__((ext_vector_type(4))) float f32x4;

static __device__ __forceinline__ float bf2f(unsigned short u) {
    return __uint_as_float(((unsigned int)u) << 16);
}
static __device__ __forceinline__ unsigned short f2bf(float f) {
    unsigned int b = __float_as_uint(f);
    return (unsigned short)((b + 0x7FFFu + ((b >> 16) & 1u)) >> 16);
}

// ---- init (pool zero + W1 pack) FUSED with per-chunk bin histogram -----------
__global__ __launch_bounds__(256) void k_init(
    const float* __restrict__ W1, unsigned short* __restrict__ w1p,
    float* __restrict__ poolS, float* __restrict__ poolC,
    const int* __restrict__ ei, int* __restrict__ binmat) {
    __shared__ int h[NBIN];
    int c = blockIdx.x;
    for (int b = threadIdx.x; b < NBIN; b += 256) h[b] = 0;
    __syncthreads();
    int e0 = c * E_CHUNK;
    int e1 = e0 + E_CHUNK; if (e1 > N_EDGES) e1 = N_EDGES;
    for (int e = e0 + threadIdx.x; e < e1; e += 256)
        atomicAdd(&h[ei[N_EDGES + e] >> 8], 1);
    // independent init work while histogram atomics settle
    int i = blockIdx.x * 256 + threadIdx.x;
    if (i < NGRP * NCLS) poolS[i] = 0.f;
    if (i < NGRP) poolC[i] = 0.f;
    if (i < FDIM * D1) {
        int ks = i >> 13;
        int r = i & 8191;
        int nt2 = r >> 9;
        int r2 = r & 511;
        int lane = r2 >> 3, e = r2 & 7;
        int k = ks * 32 + (lane >> 4) * 8 + e;
        int col = nt2 * 16 + (lane & 15);
        w1p[i] = f2bf(W1[k * D1 + col]);
    }
    __syncthreads();
    for (int b = threadIdx.x; b < NBIN; b += 256) binmat[b * NCHUNK + c] = h[b];
}

// ---- per-bin row scan: binmat[b][*] -> exclusive within-row prefix + total ---
__global__ __launch_bounds__(256) void k_binprescan(int* __restrict__ binmat,
                                                    int* __restrict__ binTot) {
    __shared__ int sh[256];
    int b = blockIdx.x, t = threadIdx.x;
    int v = (t < NCHUNK) ? binmat[b * NCHUNK + t] : 0;
    sh[t] = v;
    __syncthreads();
    for (int d = 1; d < 256; d <<= 1) {
        int tv = (t >= d) ? sh[t - d] : 0;
        __syncthreads();
        sh[t] += tv;
        __syncthreads();
    }
    if (t < NCHUNK) binmat[b * NCHUNK + t] = sh[t] - v;   // exclusive in-row
    if (t == 255) binTot[b] = sh[255];
}

// ------ GEMM1 via MFMA bf16 (no LDS): xp1b = bf16(x)@bf16(W1), fused al1 ------
__global__ __launch_bounds__(256) void k_gemm1m(
    const float* __restrict__ x, const unsigned short* __restrict__ w1p,
    const float* __restrict__ a1s, const float* __restrict__ a1d,
    unsigned short* __restrict__ xp1b, float* __restrict__ al1s,
    float* __restrict__ al1d) {
    const int l = threadIdx.x & 63;
    const int wid = threadIdx.x >> 6;
    const int wr = wid >> 1, wc = wid & 1;
    const int l15 = l & 15, l4 = l >> 4;
    const int base = blockIdx.x * 64;
    const int r0 = base + wr * 32;

    f32x4 acc[2][8] = {};
#pragma unroll
    for (int ks = 0; ks < 4; ++ks) {
        const int kk = ks * 32 + l4 * 8;
        short8 af[2];
#pragma unroll
        for (int rt = 0; rt < 2; ++rt) {
            int row = r0 + rt * 16 + l15;
            float4 v0 = make_float4(0.f, 0.f, 0.f, 0.f), v1 = v0;
            if (row < N_NODES) {
                const float* xr = x + (size_t)row * FDIM + kk;
                v0 = *(const float4*)xr;
                v1 = *(const float4*)(xr + 4);
            }
            short8 a;
            a[0] = (short)f2bf(v0.x); a[1] = (short)f2bf(v0.y);
            a[2] = (short)f2bf(v0.z); a[3] = (short)f2bf(v0.w);
            a[4] = (short)f2bf(v1.x); a[5] = (short)f2bf(v1.y);
            a[6] = (short)f2bf(v1.z); a[7] = (short)f2bf(v1.w);
            af[rt] = a;
        }
#pragma unroll
        for (int nt = 0; nt < 8; ++nt) {
            int nt2 = wc * 8 + nt;
            short8 bf_ = *(const short8*)&w1p[(size_t)((ks * 16 + nt2) * 64 + l) * 8];
            acc[0][nt] = __builtin_amdgcn_mfma_f32_16x16x32_bf16(af[0], bf_, acc[0][nt], 0, 0, 0);
            acc[1][nt] = __builtin_amdgcn_mfma_f32_16x16x32_bf16(af[1], bf_, acc[1][nt], 0, 0, 0);
        }
    }
#pragma unroll
    for (int rt = 0; rt < 2; ++rt) {
        int rbase = r0 + rt * 16 + l4 * 4;
#pragma unroll
        for (int nt = 0; nt < 8; ++nt) {
            int col = wc * 128 + nt * 16 + l15;
            f32x4 c = acc[rt][nt];
#pragma unroll
            for (int r = 0; r < 4; ++r) {
                int row = rbase + r;
                if (row < N_NODES) xp1b[(size_t)row * D1 + col] = f2bf(c[r]);
            }
        }
    }
#pragma unroll
    for (int hl = 0; hl < 4; ++hl) {
        int hg = wc * 4 + hl;
        float as0 = a1s[hg * NC + l15], as1 = a1s[hg * NC + 16 + l15];
        float ad0 = a1d[hg * NC + l15], ad1 = a1d[hg * NC + 16 + l15];
#pragma unroll
        for (int rt = 0; rt < 2; ++rt) {
            f32x4 c0 = acc[rt][2 * hl], c1 = acc[rt][2 * hl + 1];
#pragma unroll
            for (int r = 0; r < 4; ++r) {
                float ss = c0[r] * as0 + c1[r] * as1;
                float dd = c0[r] * ad0 + c1[r] * ad1;
#pragma unroll
                for (int msk = 1; msk < 16; msk <<= 1) {
                    ss += __shfl_xor(ss, msk);
                    dd += __shfl_xor(dd, msk);
                }
                int row = r0 + rt * 16 + l4 * 4 + r;
                if (l15 == 0 && row < N_NODES) {
                    al1s[row * NH + hg] = ss;
                    al1d[row * NH + hg] = dd;
                }
            }
        }
    }
}

// ---- scatter edges to bin-grouped array via LDS cursors (scan binTot inline) -
__global__ __launch_bounds__(256) void k_binscatter(const int* __restrict__ ei,
                                                    const int* __restrict__ offs,
                                                    const int* __restrict__ binTot,
                                                    int* __restrict__ binned) {
    __shared__ int cur[NBIN];
    __shared__ int sb[256];
    int c = blockIdx.x;
    int t = threadIdx.x;
    int v = (t < NBIN) ? binTot[t] : 0;
    sb[t] = v;
    __syncthreads();
    for (int d = 1; d < 256; d <<= 1) {
        int tv = (t >= d) ? sb[t - d] : 0;
        __syncthreads();
        sb[t] += tv;
        __syncthreads();
    }
    if (t < NBIN) cur[t] = (sb[t] - v) + offs[t * NCHUNK + c];
    __syncthreads();
    int e0 = c * E_CHUNK;
    int e1 = e0 + E_CHUNK; if (e1 > N_EDGES) e1 = N_EDGES;
    for (int e = e0 + t; e < e1; e += 256) {
        int s = ei[e], d = ei[N_EDGES + e];
        int pos = atomicAdd(&cur[d >> 8], 1);
        binned[pos] = s | ((d & 255) << 16);   // src < 65536
    }
}

// ---- per-bin CSR finalize (scan binTot inline) -------------------------------
__global__ __launch_bounds__(256) void k_bincsr(const int* __restrict__ binTot,
                                                const int* __restrict__ binned,
                                                int* __restrict__ rowptr,
                                                int* __restrict__ cnt,
                                                int* __restrict__ esrc) {
    __shared__ int sh[256];
    __shared__ int lcnt[256];
    __shared__ int lcur[256];
    int b = blockIdx.x;
    int t = threadIdx.x;
    int v = (t < NBIN) ? binTot[t] : 0;
    sh[t] = v;
    __syncthreads();
    for (int d = 1; d < 256; d <<= 1) {
        int tv = (t >= d) ? sh[t - d] : 0;
        __syncthreads();
        sh[t] += tv;
        __syncthreads();
    }
    int estart = (b == 0) ? 0 : sh[b - 1];
    int eend = sh[b];
    __syncthreads();
    int nbase = b * 256;
    int nin = N_NODES - nbase; if (nin > 256) nin = 256;
    lcnt[t] = 0;
    __syncthreads();
    for (int e = estart + t; e < eend; e += 256)
        atomicAdd(&lcnt[(binned[e] >> 16) & 255], 1);
    __syncthreads();
    int myc = lcnt[t] + (t < nin ? 1 : 0);   // + self loop
    sh[t] = myc;
    __syncthreads();
    for (int d = 1; d < 256; d <<= 1) {
        int tv = (t >= d) ? sh[t - d] : 0;
        __syncthreads();
        sh[t] += tv;
        __syncthreads();
    }
    int excl = sh[t] - myc;
    int outbase = estart + nbase;            // earlier bins' self-loops = nbase
    int rp = outbase + excl;
    if (t < nin) {
        rowptr[nbase + t] = rp;
        cnt[nbase + t] = myc;
        esrc[rp] = nbase + t;                // self-loop in slot 0
    }
    lcur[t] = rp + (t < nin ? 1 : 0);
    __syncthreads();
    for (int e = estart + t; e < eend; e += 256) {
        int vv = binned[e];
        int pos = atomicAdd(&lcur[(vv >> 16) & 255], 1);
        esrc[pos] = vv & 0xFFFF;
    }
}

// -- attention layer 1 (wave per dst, padded pass 2) + FUSED GEMM2/al2 epilogue
__global__ __launch_bounds__(256) void k_att1f(
    const unsigned short* __restrict__ xp1b, const float* __restrict__ al1s,
    const float* __restrict__ al1d, const float* __restrict__ b1,
    const float* __restrict__ W2, const float* __restrict__ a2s,
    const float* __restrict__ a2d, const int* __restrict__ rowptr,
    const int* __restrict__ cnt, const int* __restrict__ esrc,
    float* __restrict__ xp2, float* __restrict__ al2s, float* __restrict__ al2d) {
    __shared__ int s_src[4][64];
    __shared__ float s_alpha[4][64 * 8];
    __shared__ float h_lds[4][256];
    int wv = threadIdx.x >> 6;
    int lane = threadIdx.x & 63;
    int n = blockIdx.x * 4 + wv;          // grid exactly covers 50000 = 12500*4
    int start = rowptr[n];
    int deg = cnt[n];
    int dcap = deg < 64 ? deg : 64;
    int dpad = (dcap + 7) & ~7;
    for (int j = lane; j < dpad; j += 64)
        s_src[wv][j] = (j < dcap) ? esrc[start + j] : n;   // pad with self (hot)
    int npad = (dpad - dcap) * 8;
    if (lane < npad) s_alpha[wv][dcap * 8 + lane] = 0.f;   // zero pad alphas
    // pass 1a: leaky logits into LDS + per-(head,edge-group) max
    int h = lane & 7, eg = lane >> 3;
    float ald = al1d[n * NH + h];
    float m = -1e30f;
    for (int j = eg; j < dcap; j += 8) {
        int s = s_src[wv][j];
        float v = al1s[s * NH + h] + ald;
        v = fmaxf(v, NEG * v);                  // leaky relu (NEG<1)
        s_alpha[wv][j * 8 + h] = v;
        m = fmaxf(m, v);
    }
    if (deg > 64) {
        for (int j = 64 + eg; j < deg; j += 8) {
            int s = esrc[start + j];
            float v = al1s[s * NH + h] + ald;
            m = fmaxf(m, fmaxf(v, NEG * v));
        }
    }
    for (int msk = 8; msk < 64; msk <<= 1) m = fmaxf(m, __shfl_xor(m, msk));
    // pass 1b: single exp per (edge,head); den accumulate; alphas UNNORMALIZED
    float den = 0.f;
    for (int j = eg; j < dcap; j += 8) {
        float e = __expf(s_alpha[wv][j * 8 + h] - m);
        s_alpha[wv][j * 8 + h] = e;
        den += e;
    }
    if (deg > 64) {
        for (int j = 64 + eg; j < deg; j += 8) {
            int s = esrc[start + j];
            float v = al1s[s * NH + h] + ald;
            v = fmaxf(v, NEG * v);
            den += __expf(v - m);
        }
    }
    for (int msk = 8; msk < 64; msk <<= 1) den += __shfl_xor(den, msk);
    // pass 2: full-wave per edge; lane owns 4 channels; 8 edges, no masks
    int hh = lane >> 3;
    int cbb = lane << 3;                       // byte offset of lane's channels
    float rd2 = 1.f / __shfl(den, hh);
    float m2 = __shfl(m, hh);
    float a0 = 0.f, a1 = 0.f, a2 = 0.f, a3 = 0.f;
    for (int j0 = 0; j0 < dpad; j0 += 8) {
        int off[8];
        float aw[8];
#pragma unroll
        for (int k = 0; k < 8; ++k) {
            int s = s_src[wv][j0 + k];
            aw[k] = s_alpha[wv][(j0 + k) * 8 + hh];
            off[k] = (s << 9) + cbb;           // s*512B + lane*8B
        }
#pragma unroll
        for (int k = 0; k < 8; ++k) {
            u16x4 xv = *(const u16x4*)((const char*)xp1b + off[k]);
            a0 = fmaf(aw[k], bf2f(xv[0]), a0);
            a1 = fmaf(aw[k], bf2f(xv[1]), a1);
            a2 = fmaf(aw[k], bf2f(xv[2]), a2);
            a3 = fmaf(aw[k], bf2f(xv[3]), a3);
        }
    }
    if (deg > 64) {
        float ald2 = al1d[n * NH + hh];
        for (int j = 64; j < deg; ++j) {
            int s = esrc[start + j];
            float v = al1s[s * NH + hh] + ald2;
            v = fmaxf(v, NEG * v);
            float al = __expf(v - m2);          // unnormalized
            u16x4 xv = *(const u16x4*)((const char*)xp1b + (s << 9) + cbb);
            a0 = fmaf(al, bf2f(xv[0]), a0);
            a1 = fmaf(al, bf2f(xv[1]), a1);
            a2 = fmaf(al, bf2f(xv[2]), a2);
            a3 = fmaf(al, bf2f(xv[3]), a3);
        }
    }
    // epilogue A: normalize, bias, ELU -> fp32 h staged to per-wave LDS
    int cb = lane << 2;
    float4 bb = *(const float4*)(b1 + cb);
    a0 = fmaf(a0, rd2, bb.x);
    a1 = fmaf(a1, rd2, bb.y);
    a2 = fmaf(a2, rd2, bb.z);
    a3 = fmaf(a3, rd2, bb.w);
    a0 = a0 > 0.f ? a0 : expm1f(a0);
    a1 = a1 > 0.f ? a1 : expm1f(a1);
    a2 = a2 > 0.f ? a2 : expm1f(a2);
    a3 = a3 > 0.f ? a3 : expm1f(a3);
    *(float4*)&h_lds[wv][cb] = make_float4(a0, a1, a2, a3);
    // epilogue B: fused GEMM2 (h[256] @ W2[256][16]) + al2 logits
    // lane (o = lane&15, q = lane>>4): partial over channels q*64..q*64+63.
    // h_lds reads broadcast (4 distinct addrs); W2 reads coalesced 4x64B, L1-hot.
    int o = lane & 15, q = lane >> 4;
    const float* hp = &h_lds[wv][q * 64];
    const float* wp = W2 + (size_t)(q * 64) * NCLS + o;
    float po = 0.f;
#pragma unroll
    for (int c = 0; c < 64; ++c) po = fmaf(hp[c], wp[(size_t)c * NCLS], po);
    po += __shfl_xor(po, 16);
    po += __shfl_xor(po, 32);                  // all lanes: full sum for their o
    float ts = po * a2s[o];
    float td = po * a2d[o];
#pragma unroll
    for (int msk = 1; msk < 16; msk <<= 1) {
        ts += __shfl_xor(ts, msk);
        td += __shfl_xor(td, msk);
    }
    if (lane < 16) xp2[(size_t)n * NCLS + lane] = po;
    if (lane == 0) { al2s[n] = ts; al2d[n] = td; }
}

// -------- attention layer 2 (wave per dst node, mask-free padded pass 2) ------
__global__ __launch_bounds__(256) void k_att2(
    const float* __restrict__ xp2, const float* __restrict__ al2s,
    const float* __restrict__ al2d, const float* __restrict__ b2,
    const int* __restrict__ rowptr, const int* __restrict__ cnt,
    const int* __restrict__ esrc, float* __restrict__ out2) {
    __shared__ int s_src[4][64];
    __shared__ float s_a[4][64];
    int wave = threadIdx.x >> 6;
    int lane = threadIdx.x & 63;
    int n = blockIdx.x * 4 + wave;
    int start = rowptr[n];
    int deg = cnt[n];
    int dcap = deg < 64 ? deg : 64;
    int dpad = (dcap + 7) & ~7;
    for (int j = lane; j < dpad; j += 64)
        s_src[wave][j] = (j < dcap) ? esrc[start + j] : n;
    if (lane < dpad - dcap) s_a[wave][dcap + lane] = 0.f;
    float ald = al2d[n];
    float m = -1e30f;
    for (int j = lane; j < dcap; j += 64) {
        int s = s_src[wave][j];
        float v = al2s[s] + ald;
        v = fmaxf(v, NEG * v);
        s_a[wave][j] = v;
        m = fmaxf(m, v);
    }
    if (deg > 64) {
        for (int j = 64 + lane; j < deg; j += 64) {
            float v = al2s[esrc[start + j]] + ald;
            m = fmaxf(m, fmaxf(v, NEG * v));
        }
    }
    for (int msk = 1; msk < 64; msk <<= 1) m = fmaxf(m, __shfl_xor(m, msk));
    float den = 0.f;
    for (int j = lane; j < dcap; j += 64) {
        float e = __expf(s_a[wave][j] - m);
        s_a[wave][j] = e;
        den += e;
    }
    if (deg > 64) {
        for (int j = 64 + lane; j < deg; j += 64) {
            float v = al2s[esrc[start + j]] + ald;
            v = fmaxf(v, NEG * v);
            den += __expf(v - m);
        }
    }
    for (int msk = 1; msk < 64; msk <<= 1) den += __shfl_xor(den, msk);
    float rden = 1.f / den;
    int c = lane & 15;
    int eg = lane >> 4;                   // 4 edge slots x 16 channels
    float acc = 0.f;
    for (int j0 = 0; j0 < dpad; j0 += 8) {
#pragma unroll
        for (int k = 0; k < 2; ++k) {
            int e = j0 + eg + 4 * k;
            float aw = s_a[wave][e];
            int s = s_src[wave][e];
            acc = fmaf(aw, xp2[(size_t)s * NCLS + c], acc);
        }
    }
    if (deg > 64) {
        for (int j = 64 + eg; j < deg; j += 4) {
            int s = esrc[start + j];
            float v = al2s[s] + ald;
            v = fmaxf(v, NEG * v);
            acc += __expf(v - m) * xp2[(size_t)s * NCLS + c];
        }
    }
    acc += __shfl_xor(acc, 16);
    acc += __shfl_xor(acc, 32);
    if (lane < 16) out2[(size_t)n * NCLS + lane] = acc * rden + b2[lane];
}

// ---------------- pooling (LDS pre-aggregation, sorted batch) -----------------
__global__ __launch_bounds__(256) void k_pool(
    const float* __restrict__ out2, const int* __restrict__ batch,
    float* __restrict__ poolS, float* __restrict__ poolC) {
    __shared__ float sacc[NGRP * NCLS];
    __shared__ float scnt[NGRP];
    for (int i = threadIdx.x; i < NGRP * NCLS; i += 256) sacc[i] = 0.f;
    if (threadIdx.x < NGRP) scnt[threadIdx.x] = 0.f;
    __syncthreads();
    int n = blockIdx.x * 256 + threadIdx.x;
    if (n < N_NODES) {
        int g = batch[n];
        atomicAdd(&scnt[g], 1.f);
#pragma unroll
        for (int q = 0; q < 4; ++q) {
            float4 v = *(const float4*)(out2 + (size_t)n * NCLS + q * 4);
            atomicAdd(&sacc[g * NCLS + q * 4 + 0], v.x);
            atomicAdd(&sacc[g * NCLS + q * 4 + 1], v.y);
            atomicAdd(&sacc[g * NCLS + q * 4 + 2], v.z);
            atomicAdd(&sacc[g * NCLS + q * 4 + 3], v.w);
        }
    }
    __syncthreads();
    for (int i = threadIdx.x; i < NGRP * NCLS; i += 256)
        if (sacc[i] != 0.f) atomicAdd(&poolS[i], sacc[i]);
    if (threadIdx.x < NGRP && scnt[threadIdx.x] != 0.f)
        atomicAdd(&poolC[threadIdx.x], scnt[threadIdx.x]);
}

__global__ void k_final(const float* __restrict__ poolS,
                        const float* __restrict__ poolC, float* __restrict__ out) {
    int g = threadIdx.x;
    if (g >= NGRP) return;
    float inv = 1.f / fmaxf(poolC[g], 1.f);
    float v[NCLS];
    float m = -1e30f;
#pragma unroll
    for (int c = 0; c < NCLS; ++c) {
        v[c] = poolS[g * NCLS + c] * inv;
        m = fmaxf(m, v[c]);
    }
    float s = 0.f;
#pragma unroll
    for (int c = 0; c < NCLS; ++c) s += expf(v[c] - m);
    float lse = m + logf(s);
#pragma unroll
    for (int c = 0; c < NCLS; ++c) out[g * NCLS + c] = v[c] - lse;
}

extern "C" void kernel_launch(void* const* d_in, const int* in_sizes, int n_in,
                              void* d_out, int out_size, void* d_ws, size_t ws_size,
                              hipStream_t stream) {
    const float* x    = (const float*)d_in[0];
    const int*   ei   = (const int*)d_in[1];
    const int*   batch = (const int*)d_in[2];
    const float* W1   = (const float*)d_in[3];
    const float* a1s  = (const float*)d_in[4];
    const float* a1d  = (const float*)d_in[5];
    const float* b1   = (const float*)d_in[6];
    const float* W2   = (const float*)d_in[7];
    const float* a2s  = (const float*)d_in[8];
    const float* a2d  = (const float*)d_in[9];
    const float* b2   = (const float*)d_in[10];
    float* out = (float*)d_out;

    float* f = (float*)d_ws;
    float* al1s_ = f;  f += (size_t)N_NODES * NH;
    float* al1d_ = f;  f += (size_t)N_NODES * NH;
    float* xp2   = f;  f += (size_t)N_NODES * NCLS;
    float* al2s_ = f;  f += N_NODES;
    float* al2d_ = f;  f += N_NODES;
    float* out2  = f;  f += (size_t)N_NODES * NCLS;
    float* poolS = f;  f += NGRP * NCLS;
    float* poolC = f;  f += NGRP;
    unsigned short* xp1b = (unsigned short*)f;
    unsigned short* w1p  = xp1b + (size_t)N_NODES * D1;
    int* binmat  = (int*)(w1p + FDIM * D1);
    int* binTot  = binmat + NBIN * NCHUNK;
    int* binned  = binTot + NBIN;
    int* rowptr  = binned + N_EDGES;
    int* cnt     = rowptr + N_NODES;
    int* esrc    = cnt + N_NODES;

    k_init<<<NB_N, 256, 0, stream>>>(W1, w1p, poolS, poolC, ei, binmat);
    k_binprescan<<<NBIN, 256, 0, stream>>>(binmat, binTot);
    k_gemm1m<<<G1_BLOCKS, 256, 0, stream>>>(x, w1p, a1s, a1d, xp1b, al1s_, al1d_);
    k_binscatter<<<NCHUNK, 256, 0, stream>>>(ei, binmat, binTot, binned);
    k_bincsr<<<NBIN, 256, 0, stream>>>(binTot, binned, rowptr, cnt, esrc);
    k_att1f<<<N_NODES / 4, 256, 0, stream>>>(xp1b, al1s_, al1d_, b1, W2, a2s, a2d,
                                             rowptr, cnt, esrc, xp2, al2s_, al2d_);
    k_att2<<<N_NODES / 4, 256, 0, stream>>>(xp2, al2s_, al2d_, b2, rowptr, cnt, esrc, out2);
    k_pool<<<NB_N, 256, 0, stream>>>(out2, batch, poolS, poolC);
    k_final<<<1, 64, 0, stream>>>(poolS, poolC, out);
}